// Round 9
// baseline (1535.725 us; speedup 1.0000x reference)
//
#include <hip/hip_runtime.h>
#include <hip/hip_bf16.h>

#define BB 8
#define LL 2048
#define DM 512
#define DI 1024
#define DS 16
#define DTR 32
#define DFF 2048
#define BL (BB * LL)
#define CH 64
#define NCH (LL / CH)   // 32

typedef __hip_bfloat16 bf16;
struct bf4 { bf16 x, y, z, w; };
typedef __attribute__((ext_vector_type(8))) short short8;
typedef __attribute__((ext_vector_type(4))) float floatx4;

__device__ __forceinline__ float silu_f(float x) { return x / (1.f + __expf(-x)); }
__device__ __forceinline__ float softplus_f(float x) { return x > 20.f ? x : log1pf(__expf(x)); }
__device__ __forceinline__ float gelu_f(float x) { return 0.5f * x * (1.f + erff(x * 0.70710678118654752f)); }
__device__ __forceinline__ float b2f(bf16 v) { return __bfloat162float(v); }

__device__ __forceinline__ float4 ld4(const float* p) { return *(const float4*)p; }
__device__ __forceinline__ float4 ld4(const bf16* p) {
    bf4 v = *(const bf4*)p;
    return make_float4(b2f(v.x), b2f(v.y), b2f(v.z), b2f(v.w));
}
__device__ __forceinline__ bf4 pack4(float a, float b, float c, float d) {
    bf4 o; o.x = __float2bfloat16(a); o.y = __float2bfloat16(b);
    o.z = __float2bfloat16(c); o.w = __float2bfloat16(d); return o;
}

enum { EP_BF16, EP_SOFTPLUS, EP_GELU, EP_F32, EP_RESF, EP_ACC, EP_BIASRES };

// ---------------- fp32 -> bf16 conversion ----------------
__global__ __launch_bounds__(256) void cvt_kernel(const float* __restrict__ in,
                                                  bf16* __restrict__ out, int n4)
{
    int i = blockIdx.x * 256 + threadIdx.x;
    if (i < n4) {
        float4 v = *(const float4*)(in + (size_t)i * 4);
        *(bf4*)(out + (size_t)i * 4) = pack4(v.x, v.y, v.z, v.w);
    }
}

// ---------------- MFMA bf16 NT GEMM: C[m,n] = sum_k A[m,k]*W[n,k] ----------------
// 128xBN tile, BK=32, 256 threads (4 waves, 2x2 wave grid), 16x16x32 MFMA.
// Epilogue: LDS-staged, fully coalesced vector stores.
template <int EPI, int BN>
__global__ __launch_bounds__(256) void gemm_mfma(
    const bf16* __restrict__ A, int lda,
    const bf16* __restrict__ W, int ldb,
    void* __restrict__ Cv, int ldc, int K,
    const float* __restrict__ bias, const void* __restrict__ resv)
{
    constexpr int BM = 128, BK = 32, LDP = 40;     // LDS pitch: 40 bf16 (2-way only)
    constexpr int NA = (BM * BK / 8) / 256;
    constexpr int NW = (BN * BK / 8) / 256 > 0 ? (BN * BK / 8) / 256 : 1;
    constexpr int NT = BN / 32;
    constexpr int PITCH = BN + 8;                  // fp32 staging pitch (bank stride 8)
    constexpr int TILE_B = (BM * LDP + BN * LDP) * 2;
    constexpr int STG_B = 32 * PITCH * 4;
    constexpr int SMEM_B = TILE_B > STG_B ? TILE_B : STG_B;
    __shared__ char smem[SMEM_B];
    bf16* sA = (bf16*)smem;
    bf16* sW = ((bf16*)smem) + BM * LDP;

    const int tid = threadIdx.x;
    const int wave = tid >> 6, lane = tid & 63;
    const int col = lane & 15, quad = lane >> 4;
    const int m0 = blockIdx.y * BM, n0 = blockIdx.x * BN;
    const int wm = (wave >> 1) * 64, wn = (wave & 1) * (BN / 2);

    floatx4 acc[4][NT] = {};

    for (int k0 = 0; k0 < K; k0 += BK) {
        float4 av[NA], wv[NW];
#pragma unroll
        for (int q = 0; q < NA; ++q) {
            const int c = tid + q * 256;
            const int r = c >> 2, kc = (c & 3) << 3;
            av[q] = *(const float4*)(A + (size_t)(m0 + r) * lda + k0 + kc);
        }
#pragma unroll
        for (int q = 0; q < NW; ++q) {
            const int c = tid + q * 256;
            const int r = c >> 2, kc = (c & 3) << 3;
            wv[q] = *(const float4*)(W + (size_t)(n0 + r) * ldb + k0 + kc);
        }
        __syncthreads();
#pragma unroll
        for (int q = 0; q < NA; ++q) {
            const int c = tid + q * 256;
            const int r = c >> 2, kc = (c & 3) << 3;
            *(float4*)(sA + r * LDP + kc) = av[q];
        }
#pragma unroll
        for (int q = 0; q < NW; ++q) {
            const int c = tid + q * 256;
            const int r = c >> 2, kc = (c & 3) << 3;
            *(float4*)(sW + r * LDP + kc) = wv[q];
        }
        __syncthreads();

        short8 af[4], wf[NT];
#pragma unroll
        for (int i = 0; i < 4; ++i)
            af[i] = *(const short8*)(sA + (wm + i * 16 + col) * LDP + quad * 8);
#pragma unroll
        for (int j = 0; j < NT; ++j)
            wf[j] = *(const short8*)(sW + (wn + j * 16 + col) * LDP + quad * 8);
#pragma unroll
        for (int i = 0; i < 4; ++i)
#pragma unroll
            for (int j = 0; j < NT; ++j)
                acc[i][j] = __builtin_amdgcn_mfma_f32_16x16x32_bf16(
                    af[i], wf[j], acc[i][j], 0, 0, 0);
    }

    // ---- LDS-staged epilogue: 4 slices of 32 rows x BN cols ----
    constexpr int ELEMS = (32 * BN) / 256;   // 16 (BN=128) / 8 (BN=64)
    constexpr int TPR = BN / ELEMS;          // 8 threads per row
    float* sC = (float*)smem;
    const int row_l = tid / TPR;
    const int cg = (tid % TPR) * ELEMS;
    const int mg = m0 + (row_l & 15) + ((row_l >> 4) * 64);

#pragma unroll
    for (int i = 0; i < 4; ++i) {
        __syncthreads();
#pragma unroll
        for (int j = 0; j < NT; ++j)
#pragma unroll
            for (int r = 0; r < 4; ++r)
                sC[((wave >> 1) * 16 + quad * 4 + r) * PITCH + wn + j * 16 + col] = acc[i][j][r];
        __syncthreads();

        const int m = mg + i * 16;
        const int nb = n0 + cg;
        const size_t co = (size_t)m * ldc + nb;
        float v[ELEMS];
#pragma unroll
        for (int e = 0; e < ELEMS; ++e) v[e] = sC[row_l * PITCH + cg + e];

        if constexpr (EPI == EP_BF16 || EPI == EP_GELU) {
            bf16 ov[ELEMS];
#pragma unroll
            for (int e = 0; e < ELEMS; ++e) {
                float t = v[e];
                if constexpr (EPI == EP_GELU) t = gelu_f(t + bias[nb + e]);
                ov[e] = __float2bfloat16(t);
            }
#pragma unroll
            for (int q = 0; q < ELEMS / 8; ++q)
                *(uint4*)((bf16*)Cv + co + q * 8) = *(const uint4*)(ov + q * 8);
        } else {
#pragma unroll
            for (int e = 0; e < ELEMS; ++e) {
                if constexpr (EPI == EP_RESF)
                    v[e] += ((const float*)resv)[co + e];
                else if constexpr (EPI == EP_ACC)
                    v[e] += ((const float*)Cv)[co + e];
                else if constexpr (EPI == EP_BIASRES)
                    v[e] += bias[nb + e] + b2f(((const bf16*)resv)[co + e]);
            }
#pragma unroll
            for (int q = 0; q < ELEMS / 4; ++q) {
                float4 o = {v[q * 4 + 0], v[q * 4 + 1], v[q * 4 + 2], v[q * 4 + 3]};
                *(float4*)((float*)Cv + co + q * 4) = o;
            }
        }
    }
}

// ---------------- VALU NT GEMM (kept for dt: K=32) ----------------
template <int EPI, typename TA>
__global__ __launch_bounds__(256) void gemm_nt(
    const TA* __restrict__ A, int lda,
    const float* __restrict__ W, int ldb,
    void* __restrict__ Cv, int ldc,
    int K,
    const float* __restrict__ bias,
    const void* __restrict__ resv)
{
    __shared__ float As[16][64];
    __shared__ float Bs[16][64];
    const int tid = threadIdx.x;
    const int tx = tid & 15, ty = tid >> 4;
    const int m0 = blockIdx.y * 64, n0 = blockIdx.x * 64;
    const int lrow = tid >> 2;
    const int lcol = (tid & 3) << 2;

    const TA* Ap = A + (size_t)(m0 + lrow) * lda + lcol;
    const float* Bp = W + (size_t)(n0 + lrow) * ldb + lcol;

    float acc[4][4] = {};

    for (int k0 = 0; k0 < K; k0 += 16) {
        float4 av = ld4(Ap + k0);
        float4 bv = ld4(Bp + k0);
        __syncthreads();
        As[lcol + 0][lrow] = av.x; As[lcol + 1][lrow] = av.y;
        As[lcol + 2][lrow] = av.z; As[lcol + 3][lrow] = av.w;
        Bs[lcol + 0][lrow] = bv.x; Bs[lcol + 1][lrow] = bv.y;
        Bs[lcol + 2][lrow] = bv.z; Bs[lcol + 3][lrow] = bv.w;
        __syncthreads();
#pragma unroll
        for (int kk = 0; kk < 16; ++kk) {
            float4 a4 = *(const float4*)(&As[kk][ty << 2]);
            float4 b4 = *(const float4*)(&Bs[kk][tx << 2]);
            float aa[4] = {a4.x, a4.y, a4.z, a4.w};
            float bb[4] = {b4.x, b4.y, b4.z, b4.w};
#pragma unroll
            for (int i = 0; i < 4; ++i)
#pragma unroll
                for (int j = 0; j < 4; ++j)
                    acc[i][j] = fmaf(aa[i], bb[j], acc[i][j]);
        }
    }

#pragma unroll
    for (int i = 0; i < 4; ++i) {
        const int m = m0 + (ty << 2) + i;
        const int n = n0 + (tx << 2);
        float v[4] = {acc[i][0], acc[i][1], acc[i][2], acc[i][3]};
        const size_t co = (size_t)m * ldc + n;
        if constexpr (EPI == EP_SOFTPLUS) {
            *(bf4*)((bf16*)Cv + co) = pack4(
                softplus_f(v[0] + bias[n + 0]), softplus_f(v[1] + bias[n + 1]),
                softplus_f(v[2] + bias[n + 2]), softplus_f(v[3] + bias[n + 3]));
        } else if constexpr (EPI == EP_F32) {
            float4 o = {v[0], v[1], v[2], v[3]};
            *(float4*)((float*)Cv + co) = o;
        }
    }
}

// ---------------- depthwise conv (D_CONV=2) + SiLU ----------------
__global__ __launch_bounds__(256) void conv_silu_kernel(
    const bf16* __restrict__ xz, const float* __restrict__ cw,
    const float* __restrict__ cb, bf16* __restrict__ xic, int nbr)
{
    const int idx = blockIdx.x * 256 + threadIdx.x;
    const int c4 = (idx & 255) << 2;
    const int row = idx >> 8;
    const int l = row & (LL - 1);
    const int lnbr = l + nbr;
    const bool valid = (lnbr >= 0) && (lnbr < LL);

    const bf16* pc = xz + (size_t)row * (2 * DI) + c4;
    float4 cur = ld4(pc);
    float4 prv = make_float4(0.f, 0.f, 0.f, 0.f);
    if (valid) prv = ld4(pc + (ptrdiff_t)nbr * (2 * DI));

    float w0[4], w1[4];
#pragma unroll
    for (int q = 0; q < 4; ++q) { w0[q] = cw[(c4 + q) * 2]; w1[q] = cw[(c4 + q) * 2 + 1]; }
    float4 bb = ld4(cb + c4);

    *(bf4*)(xic + (size_t)row * DI + c4) = pack4(
        silu_f(fmaf(w0[0], prv.x, fmaf(w1[0], cur.x, bb.x))),
        silu_f(fmaf(w0[1], prv.y, fmaf(w1[1], cur.y, bb.y))),
        silu_f(fmaf(w0[2], prv.z, fmaf(w1[2], cur.z, bb.z))),
        silu_f(fmaf(w0[3], prv.w, fmaf(w1[3], cur.w, bb.w))));
}

// ---------------- chunked selective scan (CH=64, NCH=32) ----------------
__global__ __launch_bounds__(256) void scan_p1(
    const bf16* __restrict__ xic, const bf16* __restrict__ dtb,
    const float* __restrict__ xdb, const float* __restrict__ A_log,
    float* __restrict__ SD, float* __restrict__ H, int t0, int tstep)
{
    const int g = blockIdx.x * 256 + threadIdx.x;
    const int d = g & (DI - 1);
    const int rest = g >> 10;
    const int chunk = rest & (NCH - 1);
    const int b = rest >> 5;

    float a[DS], h[DS];
#pragma unroll
    for (int s = 0; s < DS; ++s) { a[s] = -__expf(A_log[d * DS + s]); h[s] = 0.f; }

    __shared__ float sB[CH][DS];
    for (int i = threadIdx.x; i < CH * DS; i += 256) {
        const int it = i >> 4, s = i & 15;
        const int t = t0 + (chunk * CH + it) * tstep;
        sB[it][s] = xdb[((size_t)(b * LL + t)) * 64 + DTR + s];
    }
    __syncthreads();

    float sumdt = 0.f;
    for (int it = 0; it < CH; ++it) {
        const int t = t0 + (chunk * CH + it) * tstep;
        const size_t row = (size_t)(b * LL + t);
        const float dtv = b2f(dtb[row * DI + d]);
        const float u = b2f(xic[row * DI + d]);
        sumdt += dtv;
        const float du = dtv * u;
#pragma unroll
        for (int s = 0; s < DS; ++s)
            h[s] = fmaf(__expf(dtv * a[s]), h[s], du * sB[it][s]);
    }
    SD[((size_t)(b * NCH + chunk)) * DI + d] = sumdt;
    const size_t base = ((size_t)((b * NCH + chunk) * DS)) * DI + d;
#pragma unroll
    for (int s = 0; s < DS; ++s)
        H[base + (size_t)s * DI] = h[s];
}

__global__ __launch_bounds__(256) void scan_p2(
    const float* __restrict__ SD, float* __restrict__ H,
    const float* __restrict__ A_log)
{
    const int g = blockIdx.x * 256 + threadIdx.x;   // 131072 threads
    const int d = g & (DI - 1);
    const int rest = g >> 10;
    const int s = rest & 15;
    const int b = rest >> 4;
    const float a = -__expf(A_log[d * DS + s]);
    float h = 0.f;
    for (int c = 0; c < NCH; ++c) {
        const float sd = SD[((size_t)(b * NCH + c)) * DI + d];
        const size_t idx = ((size_t)((b * NCH + c) * DS + s)) * DI + d;
        const float Pv = __expf(a * sd);
        const float Hv = H[idx];
        H[idx] = h;
        h = fmaf(Pv, h, Hv);
    }
}

__global__ __launch_bounds__(256) void scan_p3(
    const bf16* __restrict__ xic, const bf16* __restrict__ xz,
    const float* __restrict__ xdb, bf16* __restrict__ dty,
    const float* __restrict__ A_log, const float* __restrict__ Dskip,
    const float* __restrict__ H, int t0, int tstep)
{
    const int g = blockIdx.x * 256 + threadIdx.x;
    const int d = g & (DI - 1);
    const int rest = g >> 10;
    const int chunk = rest & (NCH - 1);
    const int b = rest >> 5;

    float a[DS], h[DS];
    const size_t base = ((size_t)((b * NCH + chunk) * DS)) * DI + d;
#pragma unroll
    for (int s = 0; s < DS; ++s) {
        a[s] = -__expf(A_log[d * DS + s]);
        h[s] = H[base + (size_t)s * DI];
    }
    const float dsk = Dskip[d];

    __shared__ float sBC[CH][2 * DS];
    for (int i = threadIdx.x; i < CH * 2 * DS; i += 256) {
        const int it = i >> 5, j = i & 31;
        const int t = t0 + (chunk * CH + it) * tstep;
        sBC[it][j] = xdb[((size_t)(b * LL + t)) * 64 + DTR + j];
    }
    __syncthreads();

    for (int it = 0; it < CH; ++it) {
        const int t = t0 + (chunk * CH + it) * tstep;
        const size_t row = (size_t)(b * LL + t);
        const float dtv = b2f(dty[row * DI + d]);
        const float u = b2f(xic[row * DI + d]);
        const float zv = b2f(xz[row * (2 * DI) + DI + d]);
        const float du = dtv * u;
        float y = 0.f;
#pragma unroll
        for (int s = 0; s < DS; ++s) {
            h[s] = fmaf(__expf(dtv * a[s]), h[s], du * sBC[it][s]);
            y = fmaf(h[s], sBC[it][DS + s], y);
        }
        y = fmaf(u, dsk, y);
        dty[row * DI + d] = __float2bfloat16(y * silu_f(zv));
    }
}

// ---------------- layernorm (fp32 in; OUT: 0=bf16 ws, 1=fp32 d_out) ----------------
template <int OUTF>
__global__ __launch_bounds__(256) void ln_kernel(
    const float* __restrict__ in, const float* __restrict__ g,
    const float* __restrict__ bta, void* __restrict__ outv)
{
    const int row = blockIdx.x;
    const int t = threadIdx.x;
    const float* p = in + (size_t)row * DM;
    const float v0 = p[t];
    const float v1 = p[t + 256];
    float sm = v0 + v1;
    float sq = v0 * v0 + v1 * v1;
#pragma unroll
    for (int off = 32; off > 0; off >>= 1) {
        sm += __shfl_xor(sm, off);
        sq += __shfl_xor(sq, off);
    }
    __shared__ float red[8];
    const int w = t >> 6;
    if ((t & 63) == 0) { red[w] = sm; red[4 + w] = sq; }
    __syncthreads();
    sm = red[0] + red[1] + red[2] + red[3];
    sq = red[4] + red[5] + red[6] + red[7];
    const float mean = sm * (1.f / DM);
    const float var = sq * (1.f / DM) - mean * mean;
    const float rstd = rsqrtf(var + 1e-5f);
    const float o0 = (v0 - mean) * rstd * g[t] + bta[t];
    const float o1 = (v1 - mean) * rstd * g[t + 256] + bta[t + 256];
    if constexpr (OUTF == 0) {
        bf16* out = (bf16*)outv;
        out[(size_t)row * DM + t] = __float2bfloat16(o0);
        out[(size_t)row * DM + t + 256] = __float2bfloat16(o1);
    } else {
        float* out = (float*)outv;
        out[(size_t)row * DM + t] = o0;
        out[(size_t)row * DM + t + 256] = o1;
    }
}

// ---------------------------------------------------------------------------
extern "C" void kernel_launch(void* const* d_in, const int* in_sizes, int n_in,
                              void* d_out, int out_size, void* d_ws, size_t ws_size,
                              hipStream_t stream)
{
    const float* x = (const float*)d_in[0];
    const float* ffn_w1 = (const float*)d_in[19];
    const float* ffn_b1 = (const float*)d_in[20];
    const float* ffn_w2 = (const float*)d_in[21];
    const float* ffn_b2 = (const float*)d_in[22];
    const float* ln1_g = (const float*)d_in[23];
    const float* ln1_b = (const float*)d_in[24];
    const float* ln2_g = (const float*)d_in[25];
    const float* ln2_b = (const float*)d_in[26];

    char* p = (char*)d_ws;
    auto alloc = [&](size_t bytes) { void* r = (void*)p; p += (bytes + 255) & ~(size_t)255; return r; };
    bf16* xz   = (bf16*)alloc((size_t)BL * 2048 * 2);
    bf16* xic  = (bf16*)alloc((size_t)BL * DI * 2);
    bf16* dtb  = (bf16*)alloc((size_t)BL * DI * 2);
    float* xdb = (float*)alloc((size_t)BL * 64 * 4);
    float* sum = (float*)alloc((size_t)BL * DM * 4);
    bf16* x1   = (bf16*)alloc((size_t)BL * DM * 2);
    bf16* xb   = (bf16*)alloc((size_t)BL * DM * 2);
    float* SD  = (float*)alloc((size_t)BB * NCH * DI * 4);
    float* Hc  = (float*)alloc((size_t)BB * NCH * DS * DI * 4);
    bf16* wip[2], *wxp[2], *wop[2];
    for (int d = 0; d < 2; ++d) {
        wip[d] = (bf16*)alloc((size_t)2 * DI * DM * 2);
        wxp[d] = (bf16*)alloc((size_t)64 * DI * 2);
        wop[d] = (bf16*)alloc((size_t)DM * DI * 2);
    }
    bf16* w1b = (bf16*)alloc((size_t)DFF * DM * 2);
    bf16* w2b = (bf16*)alloc((size_t)DM * DFF * 2);

    auto cvt = [&](const float* src, bf16* dst, size_t n) {
        int n4 = (int)(n / 4);
        cvt_kernel<<<(n4 + 255) / 256, 256, 0, stream>>>(src, dst, n4);
    };
    cvt(x, xb, (size_t)BL * DM);
    for (int d = 0; d < 2; ++d) {
        const int o = 1 + d * 9;
        cvt((const float*)d_in[o + 0], wip[d], (size_t)2 * DI * DM);
        cvt((const float*)d_in[o + 3], wxp[d], (size_t)64 * DI);
        cvt((const float*)d_in[o + 8], wop[d], (size_t)DM * DI);
    }
    cvt(ffn_w1, w1b, (size_t)DFF * DM);
    cvt(ffn_w2, w2b, (size_t)DM * DFF);

    const dim3 blk(256);
    for (int dir = 0; dir < 2; ++dir) {
        const int o = 1 + dir * 9;
        const float* conv_w = (const float*)d_in[o + 1];
        const float* conv_b = (const float*)d_in[o + 2];
        const float* dt_w   = (const float*)d_in[o + 4];
        const float* dt_b   = (const float*)d_in[o + 5];
        const float* A_log  = (const float*)d_in[o + 6];
        const float* Dskip  = (const float*)d_in[o + 7];

        const int nbr = (dir == 0) ? -1 : +1;
        const int t0 = (dir == 0) ? 0 : (LL - 1);
        const int tstep = (dir == 0) ? 1 : -1;

        gemm_mfma<EP_BF16, 128><<<dim3((2 * DI) / 128, BL / 128), blk, 0, stream>>>(
            xb, DM, wip[dir], DM, xz, 2 * DI, DM, nullptr, nullptr);
        conv_silu_kernel<<<BL, blk, 0, stream>>>(xz, conv_w, conv_b, xic, nbr);
        gemm_mfma<EP_F32, 64><<<dim3(1, BL / 128), blk, 0, stream>>>(
            xic, DI, wxp[dir], DI, xdb, 64, DI, nullptr, nullptr);
        gemm_nt<EP_SOFTPLUS, float><<<dim3(DI / 64, BL / 64), blk, 0, stream>>>(
            xdb, 64, dt_w, DTR, dtb, DI, DTR, dt_b, nullptr);

        scan_p1<<<(BB * NCH * DI) / 256, blk, 0, stream>>>(
            xic, dtb, xdb, A_log, SD, Hc, t0, tstep);
        scan_p2<<<(BB * DS * DI) / 256, blk, 0, stream>>>(SD, Hc, A_log);
        scan_p3<<<(BB * NCH * DI) / 256, blk, 0, stream>>>(
            xic, xz, xdb, dtb, A_log, Dskip, Hc, t0, tstep);

        if (dir == 0)
            gemm_mfma<EP_RESF, 128><<<dim3(DM / 128, BL / 128), blk, 0, stream>>>(
                dtb, DI, wop[dir], DI, sum, DM, DI, nullptr, x);
        else
            gemm_mfma<EP_ACC, 128><<<dim3(DM / 128, BL / 128), blk, 0, stream>>>(
                dtb, DI, wop[dir], DI, sum, DM, DI, nullptr, nullptr);
    }

    ln_kernel<0><<<BL, blk, 0, stream>>>(sum, ln1_g, ln1_b, x1);
    gemm_mfma<EP_GELU, 128><<<dim3(DFF / 128, BL / 128), blk, 0, stream>>>(
        x1, DM, w1b, DM, xz, DFF, DM, ffn_b1, nullptr);
    gemm_mfma<EP_BIASRES, 128><<<dim3(DM / 128, BL / 128), blk, 0, stream>>>(
        xz, DFF, w2b, DFF, sum, DM, DFF, ffn_b2, x1);
    ln_kernel<1><<<BL, blk, 0, stream>>>(sum, ln2_g, ln2_b, d_out);
}

// Round 10
// 1489.513 us; speedup vs baseline: 1.0310x; 1.0310x over previous
//
#include <hip/hip_runtime.h>
#include <hip/hip_bf16.h>

#define BB 8
#define LL 2048
#define DM 512
#define DI 1024
#define DS 16
#define DTR 32
#define DFF 2048
#define BL (BB * LL)
#define CH 64
#define NCH (LL / CH)   // 32

typedef __hip_bfloat16 bf16;
struct bf4 { bf16 x, y, z, w; };
typedef __attribute__((ext_vector_type(8))) short short8;
typedef __attribute__((ext_vector_type(4))) float floatx4;

__device__ __forceinline__ float silu_f(float x) { return x / (1.f + __expf(-x)); }
__device__ __forceinline__ float softplus_f(float x) { return x > 20.f ? x : log1pf(__expf(x)); }
__device__ __forceinline__ float gelu_f(float x) { return 0.5f * x * (1.f + erff(x * 0.70710678118654752f)); }
__device__ __forceinline__ float b2f(bf16 v) { return __bfloat162float(v); }

__device__ __forceinline__ float4 ld4(const float* p) { return *(const float4*)p; }
__device__ __forceinline__ float4 ld4(const bf16* p) {
    bf4 v = *(const bf4*)p;
    return make_float4(b2f(v.x), b2f(v.y), b2f(v.z), b2f(v.w));
}
__device__ __forceinline__ bf4 pack4(float a, float b, float c, float d) {
    bf4 o; o.x = __float2bfloat16(a); o.y = __float2bfloat16(b);
    o.z = __float2bfloat16(c); o.w = __float2bfloat16(d); return o;
}

enum { EP_BF16, EP_SOFTPLUS, EP_GELU, EP_F32, EP_RESF, EP_ACC, EP_BIASRES };

// ---------------- fp32 -> bf16 conversion ----------------
__global__ __launch_bounds__(256) void cvt_kernel(const float* __restrict__ in,
                                                  bf16* __restrict__ out, int n4)
{
    int i = blockIdx.x * 256 + threadIdx.x;
    if (i < n4) {
        float4 v = *(const float4*)(in + (size_t)i * 4);
        *(bf4*)(out + (size_t)i * 4) = pack4(v.x, v.y, v.z, v.w);
    }
}

// ---------------- MFMA bf16 NT GEMM: C[m,n] = sum_k A[m,k]*W[n,k] ----------------
// 128xBN tile, BK=32, 256 threads, 16x16x32 MFMA.
// blockIdx.x = m-tile (XCD-locality for A), blockIdx.y = n-tile.
// Register prefetch: loads for k+1 issued before compute of k.
template <int EPI, int BN>
__global__ __launch_bounds__(256) void gemm_mfma(
    const bf16* __restrict__ A, int lda,
    const bf16* __restrict__ W, int ldb,
    void* __restrict__ Cv, int ldc, int K,
    const float* __restrict__ bias, const void* __restrict__ resv)
{
    constexpr int BM = 128, BK = 32, LDP = 40;
    constexpr int NA = (BM * BK / 8) / 256;
    constexpr int NW = (BN * BK / 8) / 256 > 0 ? (BN * BK / 8) / 256 : 1;
    constexpr int NT = BN / 32;
    constexpr int PITCH = BN + 8;
    constexpr int TILE_B = (BM * LDP + BN * LDP) * 2;
    constexpr int STG_B = 32 * PITCH * 4;
    constexpr int SMEM_B = TILE_B > STG_B ? TILE_B : STG_B;
    __shared__ char smem[SMEM_B];
    bf16* sA = (bf16*)smem;
    bf16* sW = ((bf16*)smem) + BM * LDP;

    const int tid = threadIdx.x;
    const int wave = tid >> 6, lane = tid & 63;
    const int col = lane & 15, quad = lane >> 4;
    const int m0 = blockIdx.x * BM, n0 = blockIdx.y * BN;
    const int wm = (wave >> 1) * 64, wn = (wave & 1) * (BN / 2);

    floatx4 acc[4][NT] = {};
    float4 av[NA], wv[NW];

    // prologue loads (k0 = 0)
#pragma unroll
    for (int q = 0; q < NA; ++q) {
        const int c = tid + q * 256;
        const int r = c >> 2, kc = (c & 3) << 3;
        av[q] = *(const float4*)(A + (size_t)(m0 + r) * lda + kc);
    }
#pragma unroll
    for (int q = 0; q < NW; ++q) {
        const int c = tid + q * 256;
        const int r = c >> 2, kc = (c & 3) << 3;
        wv[q] = *(const float4*)(W + (size_t)(n0 + r) * ldb + kc);
    }

    for (int k0 = 0; k0 < K; k0 += BK) {
        __syncthreads();
#pragma unroll
        for (int q = 0; q < NA; ++q) {
            const int c = tid + q * 256;
            const int r = c >> 2, kc = (c & 3) << 3;
            *(float4*)(sA + r * LDP + kc) = av[q];
        }
#pragma unroll
        for (int q = 0; q < NW; ++q) {
            const int c = tid + q * 256;
            const int r = c >> 2, kc = (c & 3) << 3;
            *(float4*)(sW + r * LDP + kc) = wv[q];
        }
        __syncthreads();

        // prefetch next K-tile while computing this one
        if (k0 + BK < K) {
#pragma unroll
            for (int q = 0; q < NA; ++q) {
                const int c = tid + q * 256;
                const int r = c >> 2, kc = (c & 3) << 3;
                av[q] = *(const float4*)(A + (size_t)(m0 + r) * lda + k0 + BK + kc);
            }
#pragma unroll
            for (int q = 0; q < NW; ++q) {
                const int c = tid + q * 256;
                const int r = c >> 2, kc = (c & 3) << 3;
                wv[q] = *(const float4*)(W + (size_t)(n0 + r) * ldb + k0 + BK + kc);
            }
        }

        short8 af[4], wf[NT];
#pragma unroll
        for (int i = 0; i < 4; ++i)
            af[i] = *(const short8*)(sA + (wm + i * 16 + col) * LDP + quad * 8);
#pragma unroll
        for (int j = 0; j < NT; ++j)
            wf[j] = *(const short8*)(sW + (wn + j * 16 + col) * LDP + quad * 8);
#pragma unroll
        for (int i = 0; i < 4; ++i)
#pragma unroll
            for (int j = 0; j < NT; ++j)
                acc[i][j] = __builtin_amdgcn_mfma_f32_16x16x32_bf16(
                    af[i], wf[j], acc[i][j], 0, 0, 0);
    }

    // ---- LDS-staged epilogue: 4 slices of 32 rows x BN cols ----
    constexpr int ELEMS = (32 * BN) / 256;
    constexpr int TPR = BN / ELEMS;
    float* sC = (float*)smem;
    const int row_l = tid / TPR;
    const int cg = (tid % TPR) * ELEMS;
    const int mg = m0 + (row_l & 15) + ((row_l >> 4) * 64);

#pragma unroll
    for (int i = 0; i < 4; ++i) {
        __syncthreads();
#pragma unroll
        for (int j = 0; j < NT; ++j)
#pragma unroll
            for (int r = 0; r < 4; ++r)
                sC[((wave >> 1) * 16 + quad * 4 + r) * PITCH + wn + j * 16 + col] = acc[i][j][r];
        __syncthreads();

        const int m = mg + i * 16;
        const int nb = n0 + cg;
        const size_t co = (size_t)m * ldc + nb;
        float v[ELEMS];
#pragma unroll
        for (int e = 0; e < ELEMS; ++e) v[e] = sC[row_l * PITCH + cg + e];

        if constexpr (EPI == EP_BF16 || EPI == EP_GELU) {
            bf16 ov[ELEMS];
#pragma unroll
            for (int e = 0; e < ELEMS; ++e) {
                float t = v[e];
                if constexpr (EPI == EP_GELU) t = gelu_f(t + bias[nb + e]);
                ov[e] = __float2bfloat16(t);
            }
#pragma unroll
            for (int q = 0; q < ELEMS / 8; ++q)
                *(uint4*)((bf16*)Cv + co + q * 8) = *(const uint4*)(ov + q * 8);
        } else {
#pragma unroll
            for (int e = 0; e < ELEMS; ++e) {
                if constexpr (EPI == EP_RESF)
                    v[e] += ((const float*)resv)[co + e];
                else if constexpr (EPI == EP_ACC)
                    v[e] += ((const float*)Cv)[co + e];
                else if constexpr (EPI == EP_BIASRES)
                    v[e] += bias[nb + e] + b2f(((const bf16*)resv)[co + e]);
            }
#pragma unroll
            for (int q = 0; q < ELEMS / 4; ++q) {
                float4 o = {v[q * 4 + 0], v[q * 4 + 1], v[q * 4 + 2], v[q * 4 + 3]};
                *(float4*)((float*)Cv + co + q * 4) = o;
            }
        }
    }
}

// ---------------- VALU NT GEMM (kept for dt: K=32) ----------------
template <int EPI, typename TA>
__global__ __launch_bounds__(256) void gemm_nt(
    const TA* __restrict__ A, int lda,
    const float* __restrict__ W, int ldb,
    void* __restrict__ Cv, int ldc,
    int K,
    const float* __restrict__ bias,
    const void* __restrict__ resv)
{
    __shared__ float As[16][64];
    __shared__ float Bs[16][64];
    const int tid = threadIdx.x;
    const int tx = tid & 15, ty = tid >> 4;
    const int m0 = blockIdx.y * 64, n0 = blockIdx.x * 64;
    const int lrow = tid >> 2;
    const int lcol = (tid & 3) << 2;

    const TA* Ap = A + (size_t)(m0 + lrow) * lda + lcol;
    const float* Bp = W + (size_t)(n0 + lrow) * ldb + lcol;

    float acc[4][4] = {};

    for (int k0 = 0; k0 < K; k0 += 16) {
        float4 av = ld4(Ap + k0);
        float4 bv = ld4(Bp + k0);
        __syncthreads();
        As[lcol + 0][lrow] = av.x; As[lcol + 1][lrow] = av.y;
        As[lcol + 2][lrow] = av.z; As[lcol + 3][lrow] = av.w;
        Bs[lcol + 0][lrow] = bv.x; Bs[lcol + 1][lrow] = bv.y;
        Bs[lcol + 2][lrow] = bv.z; Bs[lcol + 3][lrow] = bv.w;
        __syncthreads();
#pragma unroll
        for (int kk = 0; kk < 16; ++kk) {
            float4 a4 = *(const float4*)(&As[kk][ty << 2]);
            float4 b4 = *(const float4*)(&Bs[kk][tx << 2]);
            float aa[4] = {a4.x, a4.y, a4.z, a4.w};
            float bb[4] = {b4.x, b4.y, b4.z, b4.w};
#pragma unroll
            for (int i = 0; i < 4; ++i)
#pragma unroll
                for (int j = 0; j < 4; ++j)
                    acc[i][j] = fmaf(aa[i], bb[j], acc[i][j]);
        }
    }

#pragma unroll
    for (int i = 0; i < 4; ++i) {
        const int m = m0 + (ty << 2) + i;
        const int n = n0 + (tx << 2);
        float v[4] = {acc[i][0], acc[i][1], acc[i][2], acc[i][3]};
        const size_t co = (size_t)m * ldc + n;
        if constexpr (EPI == EP_SOFTPLUS) {
            *(bf4*)((bf16*)Cv + co) = pack4(
                softplus_f(v[0] + bias[n + 0]), softplus_f(v[1] + bias[n + 1]),
                softplus_f(v[2] + bias[n + 2]), softplus_f(v[3] + bias[n + 3]));
        } else if constexpr (EPI == EP_F32) {
            float4 o = {v[0], v[1], v[2], v[3]};
            *(float4*)((float*)Cv + co) = o;
        }
    }
}

// ---------------- depthwise conv (D_CONV=2) + SiLU ----------------
__global__ __launch_bounds__(256) void conv_silu_kernel(
    const bf16* __restrict__ xz, const float* __restrict__ cw,
    const float* __restrict__ cb, bf16* __restrict__ xic, int nbr)
{
    const int idx = blockIdx.x * 256 + threadIdx.x;
    const int c4 = (idx & 255) << 2;
    const int row = idx >> 8;
    const int l = row & (LL - 1);
    const int lnbr = l + nbr;
    const bool valid = (lnbr >= 0) && (lnbr < LL);

    const bf16* pc = xz + (size_t)row * (2 * DI) + c4;
    float4 cur = ld4(pc);
    float4 prv = make_float4(0.f, 0.f, 0.f, 0.f);
    if (valid) prv = ld4(pc + (ptrdiff_t)nbr * (2 * DI));

    float w0[4], w1[4];
#pragma unroll
    for (int q = 0; q < 4; ++q) { w0[q] = cw[(c4 + q) * 2]; w1[q] = cw[(c4 + q) * 2 + 1]; }
    float4 bb = ld4(cb + c4);

    *(bf4*)(xic + (size_t)row * DI + c4) = pack4(
        silu_f(fmaf(w0[0], prv.x, fmaf(w1[0], cur.x, bb.x))),
        silu_f(fmaf(w0[1], prv.y, fmaf(w1[1], cur.y, bb.y))),
        silu_f(fmaf(w0[2], prv.z, fmaf(w1[2], cur.z, bb.z))),
        silu_f(fmaf(w0[3], prv.w, fmaf(w1[3], cur.w, bb.w))));
}

// ---------------- chunked selective scan (CH=64, NCH=32) ----------------
__global__ __launch_bounds__(256) void scan_p1(
    const bf16* __restrict__ xic, const bf16* __restrict__ dtb,
    const float* __restrict__ xdb, const float* __restrict__ A_log,
    float* __restrict__ SD, float* __restrict__ H, int t0, int tstep)
{
    const int g = blockIdx.x * 256 + threadIdx.x;
    const int d = g & (DI - 1);
    const int rest = g >> 10;
    const int chunk = rest & (NCH - 1);
    const int b = rest >> 5;

    float a[DS], h[DS];
#pragma unroll
    for (int s = 0; s < DS; ++s) { a[s] = -__expf(A_log[d * DS + s]); h[s] = 0.f; }

    __shared__ float sB[CH][DS];
    for (int i = threadIdx.x; i < CH * DS; i += 256) {
        const int it = i >> 4, s = i & 15;
        const int t = t0 + (chunk * CH + it) * tstep;
        sB[it][s] = xdb[((size_t)(b * LL + t)) * 64 + DTR + s];
    }
    __syncthreads();

    float sumdt = 0.f;
    for (int it = 0; it < CH; ++it) {
        const int t = t0 + (chunk * CH + it) * tstep;
        const size_t row = (size_t)(b * LL + t);
        const float dtv = b2f(dtb[row * DI + d]);
        const float u = b2f(xic[row * DI + d]);
        sumdt += dtv;
        const float du = dtv * u;
#pragma unroll
        for (int s = 0; s < DS; ++s)
            h[s] = fmaf(__expf(dtv * a[s]), h[s], du * sB[it][s]);
    }
    SD[((size_t)(b * NCH + chunk)) * DI + d] = sumdt;
    const size_t base = ((size_t)((b * NCH + chunk) * DS)) * DI + d;
#pragma unroll
    for (int s = 0; s < DS; ++s)
        H[base + (size_t)s * DI] = h[s];
}

__global__ __launch_bounds__(256) void scan_p2(
    const float* __restrict__ SD, float* __restrict__ H,
    const float* __restrict__ A_log)
{
    const int g = blockIdx.x * 256 + threadIdx.x;   // 131072 threads
    const int d = g & (DI - 1);
    const int rest = g >> 10;
    const int s = rest & 15;
    const int b = rest >> 4;
    const float a = -__expf(A_log[d * DS + s]);
    float h = 0.f;
    for (int c = 0; c < NCH; ++c) {
        const float sd = SD[((size_t)(b * NCH + c)) * DI + d];
        const size_t idx = ((size_t)((b * NCH + c) * DS + s)) * DI + d;
        const float Pv = __expf(a * sd);
        const float Hv = H[idx];
        H[idx] = h;
        h = fmaf(Pv, h, Hv);
    }
}

__global__ __launch_bounds__(256) void scan_p3(
    const bf16* __restrict__ xic, const bf16* __restrict__ xz,
    const float* __restrict__ xdb, bf16* __restrict__ dty,
    const float* __restrict__ A_log, const float* __restrict__ Dskip,
    const float* __restrict__ H, int t0, int tstep)
{
    const int g = blockIdx.x * 256 + threadIdx.x;
    const int d = g & (DI - 1);
    const int rest = g >> 10;
    const int chunk = rest & (NCH - 1);
    const int b = rest >> 5;

    float a[DS], h[DS];
    const size_t base = ((size_t)((b * NCH + chunk) * DS)) * DI + d;
#pragma unroll
    for (int s = 0; s < DS; ++s) {
        a[s] = -__expf(A_log[d * DS + s]);
        h[s] = H[base + (size_t)s * DI];
    }
    const float dsk = Dskip[d];

    __shared__ float sBC[CH][2 * DS];
    for (int i = threadIdx.x; i < CH * 2 * DS; i += 256) {
        const int it = i >> 5, j = i & 31;
        const int t = t0 + (chunk * CH + it) * tstep;
        sBC[it][j] = xdb[((size_t)(b * LL + t)) * 64 + DTR + j];
    }
    __syncthreads();

    for (int it = 0; it < CH; ++it) {
        const int t = t0 + (chunk * CH + it) * tstep;
        const size_t row = (size_t)(b * LL + t);
        const float dtv = b2f(dty[row * DI + d]);
        const float u = b2f(xic[row * DI + d]);
        const float zv = b2f(xz[row * (2 * DI) + DI + d]);
        const float du = dtv * u;
        float y = 0.f;
#pragma unroll
        for (int s = 0; s < DS; ++s) {
            h[s] = fmaf(__expf(dtv * a[s]), h[s], du * sBC[it][s]);
            y = fmaf(h[s], sBC[it][DS + s], y);
        }
        y = fmaf(u, dsk, y);
        dty[row * DI + d] = __float2bfloat16(y * silu_f(zv));
    }
}

// ---------------- layernorm (fp32 in; OUT: 0=bf16 ws, 1=fp32 d_out) ----------------
template <int OUTF>
__global__ __launch_bounds__(256) void ln_kernel(
    const float* __restrict__ in, const float* __restrict__ g,
    const float* __restrict__ bta, void* __restrict__ outv)
{
    const int row = blockIdx.x;
    const int t = threadIdx.x;
    const float* p = in + (size_t)row * DM;
    const float v0 = p[t];
    const float v1 = p[t + 256];
    float sm = v0 + v1;
    float sq = v0 * v0 + v1 * v1;
#pragma unroll
    for (int off = 32; off > 0; off >>= 1) {
        sm += __shfl_xor(sm, off);
        sq += __shfl_xor(sq, off);
    }
    __shared__ float red[8];
    const int w = t >> 6;
    if ((t & 63) == 0) { red[w] = sm; red[4 + w] = sq; }
    __syncthreads();
    sm = red[0] + red[1] + red[2] + red[3];
    sq = red[4] + red[5] + red[6] + red[7];
    const float mean = sm * (1.f / DM);
    const float var = sq * (1.f / DM) - mean * mean;
    const float rstd = rsqrtf(var + 1e-5f);
    const float o0 = (v0 - mean) * rstd * g[t] + bta[t];
    const float o1 = (v1 - mean) * rstd * g[t + 256] + bta[t + 256];
    if constexpr (OUTF == 0) {
        bf16* out = (bf16*)outv;
        out[(size_t)row * DM + t] = __float2bfloat16(o0);
        out[(size_t)row * DM + t + 256] = __float2bfloat16(o1);
    } else {
        float* out = (float*)outv;
        out[(size_t)row * DM + t] = o0;
        out[(size_t)row * DM + t + 256] = o1;
    }
}

// ---------------------------------------------------------------------------
extern "C" void kernel_launch(void* const* d_in, const int* in_sizes, int n_in,
                              void* d_out, int out_size, void* d_ws, size_t ws_size,
                              hipStream_t stream)
{
    const float* x = (const float*)d_in[0];
    const float* ffn_w1 = (const float*)d_in[19];
    const float* ffn_b1 = (const float*)d_in[20];
    const float* ffn_w2 = (const float*)d_in[21];
    const float* ffn_b2 = (const float*)d_in[22];
    const float* ln1_g = (const float*)d_in[23];
    const float* ln1_b = (const float*)d_in[24];
    const float* ln2_g = (const float*)d_in[25];
    const float* ln2_b = (const float*)d_in[26];

    char* p = (char*)d_ws;
    auto alloc = [&](size_t bytes) { void* r = (void*)p; p += (bytes + 255) & ~(size_t)255; return r; };
    bf16* xz   = (bf16*)alloc((size_t)BL * 2048 * 2);
    bf16* xic  = (bf16*)alloc((size_t)BL * DI * 2);
    bf16* dtb  = (bf16*)alloc((size_t)BL * DI * 2);
    float* xdb = (float*)alloc((size_t)BL * 64 * 4);
    float* sum = (float*)alloc((size_t)BL * DM * 4);
    bf16* x1   = (bf16*)alloc((size_t)BL * DM * 2);
    bf16* xb   = (bf16*)alloc((size_t)BL * DM * 2);
    float* SD  = (float*)alloc((size_t)BB * NCH * DI * 4);
    float* Hc  = (float*)alloc((size_t)BB * NCH * DS * DI * 4);
    bf16* wip[2], *wxp[2], *wop[2];
    for (int d = 0; d < 2; ++d) {
        wip[d] = (bf16*)alloc((size_t)2 * DI * DM * 2);
        wxp[d] = (bf16*)alloc((size_t)64 * DI * 2);
        wop[d] = (bf16*)alloc((size_t)DM * DI * 2);
    }
    bf16* w1b = (bf16*)alloc((size_t)DFF * DM * 2);
    bf16* w2b = (bf16*)alloc((size_t)DM * DFF * 2);

    auto cvt = [&](const float* src, bf16* dst, size_t n) {
        int n4 = (int)(n / 4);
        cvt_kernel<<<(n4 + 255) / 256, 256, 0, stream>>>(src, dst, n4);
    };
    cvt(x, xb, (size_t)BL * DM);
    for (int d = 0; d < 2; ++d) {
        const int o = 1 + d * 9;
        cvt((const float*)d_in[o + 0], wip[d], (size_t)2 * DI * DM);
        cvt((const float*)d_in[o + 3], wxp[d], (size_t)64 * DI);
        cvt((const float*)d_in[o + 8], wop[d], (size_t)DM * DI);
    }
    cvt(ffn_w1, w1b, (size_t)DFF * DM);
    cvt(ffn_w2, w2b, (size_t)DM * DFF);

    const dim3 blk(256);
    for (int dir = 0; dir < 2; ++dir) {
        const int o = 1 + dir * 9;
        const float* conv_w = (const float*)d_in[o + 1];
        const float* conv_b = (const float*)d_in[o + 2];
        const float* dt_w   = (const float*)d_in[o + 4];
        const float* dt_b   = (const float*)d_in[o + 5];
        const float* A_log  = (const float*)d_in[o + 6];
        const float* Dskip  = (const float*)d_in[o + 7];

        const int nbr = (dir == 0) ? -1 : +1;
        const int t0 = (dir == 0) ? 0 : (LL - 1);
        const int tstep = (dir == 0) ? 1 : -1;

        // grids: x = m-tiles (BL/128 = 128), y = n-tiles
        gemm_mfma<EP_BF16, 128><<<dim3(BL / 128, (2 * DI) / 128), blk, 0, stream>>>(
            xb, DM, wip[dir], DM, xz, 2 * DI, DM, nullptr, nullptr);
        conv_silu_kernel<<<BL, blk, 0, stream>>>(xz, conv_w, conv_b, xic, nbr);
        gemm_mfma<EP_F32, 64><<<dim3(BL / 128, 1), blk, 0, stream>>>(
            xic, DI, wxp[dir], DI, xdb, 64, DI, nullptr, nullptr);
        gemm_nt<EP_SOFTPLUS, float><<<dim3(DI / 64, BL / 64), blk, 0, stream>>>(
            xdb, 64, dt_w, DTR, dtb, DI, DTR, dt_b, nullptr);

        scan_p1<<<(BB * NCH * DI) / 256, blk, 0, stream>>>(
            xic, dtb, xdb, A_log, SD, Hc, t0, tstep);
        scan_p2<<<(BB * DS * DI) / 256, blk, 0, stream>>>(SD, Hc, A_log);
        scan_p3<<<(BB * NCH * DI) / 256, blk, 0, stream>>>(
            xic, xz, xdb, dtb, A_log, Dskip, Hc, t0, tstep);

        if (dir == 0)
            gemm_mfma<EP_RESF, 128><<<dim3(BL / 128, DM / 128), blk, 0, stream>>>(
                dtb, DI, wop[dir], DI, sum, DM, DI, nullptr, x);
        else
            gemm_mfma<EP_ACC, 128><<<dim3(BL / 128, DM / 128), blk, 0, stream>>>(
                dtb, DI, wop[dir], DI, sum, DM, DI, nullptr, nullptr);
    }

    ln_kernel<0><<<BL, blk, 0, stream>>>(sum, ln1_g, ln1_b, x1);
    gemm_mfma<EP_GELU, 128><<<dim3(BL / 128, DFF / 128), blk, 0, stream>>>(
        x1, DM, w1b, DM, xz, DFF, DM, ffn_b1, nullptr);
    gemm_mfma<EP_BIASRES, 128><<<dim3(BL / 128, DM / 128), blk, 0, stream>>>(
        xz, DFF, w2b, DFF, sum, DM, DFF, ffn_b2, x1);
    ln_kernel<1><<<BL, blk, 0, stream>>>(sum, ln2_g, ln2_b, d_out);
}

// Round 11
// 967.748 us; speedup vs baseline: 1.5869x; 1.5392x over previous
//
#include <hip/hip_runtime.h>
#include <hip/hip_bf16.h>

#define BB 8
#define LL 2048
#define DM 512
#define DI 1024
#define DS 16
#define DTR 32
#define DFF 2048
#define BL (BB * LL)
#define CH 64
#define NCH (LL / CH)   // 32

typedef __hip_bfloat16 bf16;
struct bf4 { bf16 x, y, z, w; };
typedef __attribute__((ext_vector_type(8))) short short8;
typedef __attribute__((ext_vector_type(4))) float floatx4;

__device__ __forceinline__ float silu_f(float x) { return x / (1.f + __expf(-x)); }
__device__ __forceinline__ float softplus_f(float x) { return x > 20.f ? x : log1pf(__expf(x)); }
__device__ __forceinline__ float gelu_f(float x) { return 0.5f * x * (1.f + erff(x * 0.70710678118654752f)); }
__device__ __forceinline__ float b2f(bf16 v) { return __bfloat162float(v); }

__device__ __forceinline__ float4 ld4(const float* p) { return *(const float4*)p; }
__device__ __forceinline__ float4 ld4(const bf16* p) {
    bf4 v = *(const bf4*)p;
    return make_float4(b2f(v.x), b2f(v.y), b2f(v.z), b2f(v.w));
}
__device__ __forceinline__ bf4 pack4(float a, float b, float c, float d) {
    bf4 o; o.x = __float2bfloat16(a); o.y = __float2bfloat16(b);
    o.z = __float2bfloat16(c); o.w = __float2bfloat16(d); return o;
}

// async global->LDS, 16 B per lane; LDS dest = wave-uniform base + lane*16
__device__ __forceinline__ void gll16(const bf16* g, bf16* l) {
    __builtin_amdgcn_global_load_lds(
        (const __attribute__((address_space(1))) void*)g,
        (__attribute__((address_space(3))) void*)l, 16, 0, 0);
}

enum { EP_BF16, EP_SOFTPLUS, EP_GELU, EP_F32, EP_RESF, EP_ACC, EP_BIASRES };

// ---------------- fp32 -> bf16 conversion ----------------
__global__ __launch_bounds__(256) void cvt_kernel(const float* __restrict__ in,
                                                  bf16* __restrict__ out, int n4)
{
    int i = blockIdx.x * 256 + threadIdx.x;
    if (i < n4) {
        float4 v = *(const float4*)(in + (size_t)i * 4);
        *(bf4*)(out + (size_t)i * 4) = pack4(v.x, v.y, v.z, v.w);
    }
}

// ---------------- MFMA bf16 NT GEMM: C[m,n] = sum_k A[m,k]*W[n,k] ----------------
// 128xBN tile, BK=32, 256 threads, 16x16x32 MFMA.
// Staging via global_load_lds (async, width 16). LDS tile unpadded (64 B/row);
// XOR swizzle baked into the per-lane FETCH address so fragment ds_read_b128 is
// conflict-free: logical (row, kq) lives at byte row*64 + ((kq ^ ((row>>1)&3))*16).
template <int EPI, int BN>
__global__ __launch_bounds__(256) void gemm_mfma(
    const bf16* __restrict__ A, int lda,
    const bf16* __restrict__ W, int ldb,
    void* __restrict__ Cv, int ldc, int K,
    const float* __restrict__ bias, const void* __restrict__ resv)
{
    constexpr int BM = 128, BK = 32;
    constexpr int NT = BN / 32;            // n-frags per wave
    constexpr int ACH_W = 2;               // A 1KB-chunks per wave (8 total)
    constexpr int WCH_W = (BN / 16) / 4;   // W chunks per wave (2 or 1)
    constexpr int PITCH = BN + 8;          // fp32 epilogue staging pitch
    constexpr int TILE_B = BM * 64 + BN * 64;
    constexpr int STG_B = 32 * PITCH * 4;
    constexpr int SMEM_B = TILE_B > STG_B ? TILE_B : STG_B;
    __shared__ __align__(1024) char smem[SMEM_B];
    bf16* sA = (bf16*)smem;
    bf16* sW = (bf16*)(smem + BM * 64);

    const int tid = threadIdx.x;
    const int wv = tid >> 6, ln = tid & 63;
    const int rloc = ln >> 2;                          // staging row-within-chunk
    const int kperm = (ln & 3) ^ ((ln >> 3) & 3);      // swizzled k-chunk fetch
    const int c = ln & 15, q4 = ln >> 4;               // fragment col / k-quad
    const int swz8 = 8 * (q4 ^ ((c >> 1) & 3));        // swizzled read offset (bf16)
    const int m0 = blockIdx.x * BM, n0 = blockIdx.y * BN;
    const int wm = (wv >> 1) * 64, wn = (wv & 1) * (BN / 2);

    floatx4 acc[4][NT] = {};

    for (int k0 = 0; k0 < K; k0 += BK) {
        __syncthreads();                   // readers of previous tile done
#pragma unroll
        for (int q = 0; q < ACH_W; ++q) {
            const int chunk = wv * ACH_W + q;
            gll16(A + (size_t)(m0 + chunk * 16 + rloc) * lda + k0 + kperm * 8,
                  sA + chunk * 512);
        }
#pragma unroll
        for (int q = 0; q < WCH_W; ++q) {
            const int chunk = wv * WCH_W + q;
            gll16(W + (size_t)(n0 + chunk * 16 + rloc) * ldb + k0 + kperm * 8,
                  sW + chunk * 512);
        }
        __syncthreads();                   // drains vmcnt(0) then barrier

        short8 af[4], wf[NT];
#pragma unroll
        for (int i = 0; i < 4; ++i)
            af[i] = *(const short8*)(sA + (wm + i * 16 + c) * 32 + swz8);
#pragma unroll
        for (int j = 0; j < NT; ++j)
            wf[j] = *(const short8*)(sW + (wn + j * 16 + c) * 32 + swz8);
#pragma unroll
        for (int i = 0; i < 4; ++i)
#pragma unroll
            for (int j = 0; j < NT; ++j)
                acc[i][j] = __builtin_amdgcn_mfma_f32_16x16x32_bf16(
                    af[i], wf[j], acc[i][j], 0, 0, 0);
    }

    // ---- LDS-staged epilogue: 4 slices of 32 rows x BN cols ----
    constexpr int ELEMS = (32 * BN) / 256;
    constexpr int TPR = BN / ELEMS;
    float* sC = (float*)smem;
    const int row_l = tid / TPR;
    const int cg = (tid % TPR) * ELEMS;
    const int mg = m0 + (row_l & 15) + ((row_l >> 4) * 64);

#pragma unroll
    for (int i = 0; i < 4; ++i) {
        __syncthreads();
#pragma unroll
        for (int j = 0; j < NT; ++j)
#pragma unroll
            for (int r = 0; r < 4; ++r)
                sC[((wv >> 1) * 16 + q4 * 4 + r) * PITCH + wn + j * 16 + c] = acc[i][j][r];
        __syncthreads();

        const int m = mg + i * 16;
        const int nb = n0 + cg;
        const size_t co = (size_t)m * ldc + nb;
        float v[ELEMS];
#pragma unroll
        for (int e = 0; e < ELEMS; ++e) v[e] = sC[row_l * PITCH + cg + e];

        if constexpr (EPI == EP_BF16 || EPI == EP_GELU) {
            bf16 ov[ELEMS];
#pragma unroll
            for (int e = 0; e < ELEMS; ++e) {
                float t = v[e];
                if constexpr (EPI == EP_GELU) t = gelu_f(t + bias[nb + e]);
                ov[e] = __float2bfloat16(t);
            }
#pragma unroll
            for (int q = 0; q < ELEMS / 8; ++q)
                *(uint4*)((bf16*)Cv + co + q * 8) = *(const uint4*)(ov + q * 8);
        } else {
#pragma unroll
            for (int e = 0; e < ELEMS; ++e) {
                if constexpr (EPI == EP_RESF)
                    v[e] += ((const float*)resv)[co + e];
                else if constexpr (EPI == EP_ACC)
                    v[e] += ((const float*)Cv)[co + e];
                else if constexpr (EPI == EP_BIASRES)
                    v[e] += bias[nb + e] + b2f(((const bf16*)resv)[co + e]);
            }
#pragma unroll
            for (int q = 0; q < ELEMS / 4; ++q) {
                float4 o = {v[q * 4 + 0], v[q * 4 + 1], v[q * 4 + 2], v[q * 4 + 3]};
                *(float4*)((float*)Cv + co + q * 4) = o;
            }
        }
    }
}

// ---------------- VALU NT GEMM (kept for dt: K=32) ----------------
template <int EPI, typename TA>
__global__ __launch_bounds__(256) void gemm_nt(
    const TA* __restrict__ A, int lda,
    const float* __restrict__ W, int ldb,
    void* __restrict__ Cv, int ldc,
    int K,
    const float* __restrict__ bias,
    const void* __restrict__ resv)
{
    __shared__ float As[16][64];
    __shared__ float Bs[16][64];
    const int tid = threadIdx.x;
    const int tx = tid & 15, ty = tid >> 4;
    const int m0 = blockIdx.y * 64, n0 = blockIdx.x * 64;
    const int lrow = tid >> 2;
    const int lcol = (tid & 3) << 2;

    const TA* Ap = A + (size_t)(m0 + lrow) * lda + lcol;
    const float* Bp = W + (size_t)(n0 + lrow) * ldb + lcol;

    float acc[4][4] = {};

    for (int k0 = 0; k0 < K; k0 += 16) {
        float4 av = ld4(Ap + k0);
        float4 bv = ld4(Bp + k0);
        __syncthreads();
        As[lcol + 0][lrow] = av.x; As[lcol + 1][lrow] = av.y;
        As[lcol + 2][lrow] = av.z; As[lcol + 3][lrow] = av.w;
        Bs[lcol + 0][lrow] = bv.x; Bs[lcol + 1][lrow] = bv.y;
        Bs[lcol + 2][lrow] = bv.z; Bs[lcol + 3][lrow] = bv.w;
        __syncthreads();
#pragma unroll
        for (int kk = 0; kk < 16; ++kk) {
            float4 a4 = *(const float4*)(&As[kk][ty << 2]);
            float4 b4 = *(const float4*)(&Bs[kk][tx << 2]);
            float aa[4] = {a4.x, a4.y, a4.z, a4.w};
            float bb[4] = {b4.x, b4.y, b4.z, b4.w};
#pragma unroll
            for (int i = 0; i < 4; ++i)
#pragma unroll
                for (int j = 0; j < 4; ++j)
                    acc[i][j] = fmaf(aa[i], bb[j], acc[i][j]);
        }
    }

#pragma unroll
    for (int i = 0; i < 4; ++i) {
        const int m = m0 + (ty << 2) + i;
        const int n = n0 + (tx << 2);
        float v[4] = {acc[i][0], acc[i][1], acc[i][2], acc[i][3]};
        const size_t co = (size_t)m * ldc + n;
        if constexpr (EPI == EP_SOFTPLUS) {
            *(bf4*)((bf16*)Cv + co) = pack4(
                softplus_f(v[0] + bias[n + 0]), softplus_f(v[1] + bias[n + 1]),
                softplus_f(v[2] + bias[n + 2]), softplus_f(v[3] + bias[n + 3]));
        } else if constexpr (EPI == EP_F32) {
            float4 o = {v[0], v[1], v[2], v[3]};
            *(float4*)((float*)Cv + co) = o;
        }
    }
}

// ---------------- depthwise conv (D_CONV=2) + SiLU ----------------
__global__ __launch_bounds__(256) void conv_silu_kernel(
    const bf16* __restrict__ xz, const float* __restrict__ cw,
    const float* __restrict__ cb, bf16* __restrict__ xic, int nbr)
{
    const int idx = blockIdx.x * 256 + threadIdx.x;
    const int c4 = (idx & 255) << 2;
    const int row = idx >> 8;
    const int l = row & (LL - 1);
    const int lnbr = l + nbr;
    const bool valid = (lnbr >= 0) && (lnbr < LL);

    const bf16* pc = xz + (size_t)row * (2 * DI) + c4;
    float4 cur = ld4(pc);
    float4 prv = make_float4(0.f, 0.f, 0.f, 0.f);
    if (valid) prv = ld4(pc + (ptrdiff_t)nbr * (2 * DI));

    float w0[4], w1[4];
#pragma unroll
    for (int q = 0; q < 4; ++q) { w0[q] = cw[(c4 + q) * 2]; w1[q] = cw[(c4 + q) * 2 + 1]; }
    float4 bb = ld4(cb + c4);

    *(bf4*)(xic + (size_t)row * DI + c4) = pack4(
        silu_f(fmaf(w0[0], prv.x, fmaf(w1[0], cur.x, bb.x))),
        silu_f(fmaf(w0[1], prv.y, fmaf(w1[1], cur.y, bb.y))),
        silu_f(fmaf(w0[2], prv.z, fmaf(w1[2], cur.z, bb.z))),
        silu_f(fmaf(w0[3], prv.w, fmaf(w1[3], cur.w, bb.w))));
}

// ---------------- chunked selective scan (CH=64, NCH=32) ----------------
__global__ __launch_bounds__(256) void scan_p1(
    const bf16* __restrict__ xic, const bf16* __restrict__ dtb,
    const float* __restrict__ xdb, const float* __restrict__ A_log,
    float* __restrict__ SD, float* __restrict__ H, int t0, int tstep)
{
    const int g = blockIdx.x * 256 + threadIdx.x;
    const int d = g & (DI - 1);
    const int rest = g >> 10;
    const int chunk = rest & (NCH - 1);
    const int b = rest >> 5;

    float a[DS], h[DS];
#pragma unroll
    for (int s = 0; s < DS; ++s) { a[s] = -__expf(A_log[d * DS + s]); h[s] = 0.f; }

    __shared__ float sB[CH][DS];
    for (int i = threadIdx.x; i < CH * DS; i += 256) {
        const int it = i >> 4, s = i & 15;
        const int t = t0 + (chunk * CH + it) * tstep;
        sB[it][s] = xdb[((size_t)(b * LL + t)) * 64 + DTR + s];
    }
    __syncthreads();

    float sumdt = 0.f;
    for (int it = 0; it < CH; ++it) {
        const int t = t0 + (chunk * CH + it) * tstep;
        const size_t row = (size_t)(b * LL + t);
        const float dtv = b2f(dtb[row * DI + d]);
        const float u = b2f(xic[row * DI + d]);
        sumdt += dtv;
        const float du = dtv * u;
#pragma unroll
        for (int s = 0; s < DS; ++s)
            h[s] = fmaf(__expf(dtv * a[s]), h[s], du * sB[it][s]);
    }
    SD[((size_t)(b * NCH + chunk)) * DI + d] = sumdt;
    const size_t base = ((size_t)((b * NCH + chunk) * DS)) * DI + d;
#pragma unroll
    for (int s = 0; s < DS; ++s)
        H[base + (size_t)s * DI] = h[s];
}

__global__ __launch_bounds__(256) void scan_p2(
    const float* __restrict__ SD, float* __restrict__ H,
    const float* __restrict__ A_log)
{
    const int g = blockIdx.x * 256 + threadIdx.x;   // 131072 threads
    const int d = g & (DI - 1);
    const int rest = g >> 10;
    const int s = rest & 15;
    const int b = rest >> 4;
    const float a = -__expf(A_log[d * DS + s]);
    float h = 0.f;
    for (int c = 0; c < NCH; ++c) {
        const float sd = SD[((size_t)(b * NCH + c)) * DI + d];
        const size_t idx = ((size_t)((b * NCH + c) * DS + s)) * DI + d;
        const float Pv = __expf(a * sd);
        const float Hv = H[idx];
        H[idx] = h;
        h = fmaf(Pv, h, Hv);
    }
}

__global__ __launch_bounds__(256) void scan_p3(
    const bf16* __restrict__ xic, const bf16* __restrict__ xz,
    const float* __restrict__ xdb, bf16* __restrict__ dty,
    const float* __restrict__ A_log, const float* __restrict__ Dskip,
    const float* __restrict__ H, int t0, int tstep)
{
    const int g = blockIdx.x * 256 + threadIdx.x;
    const int d = g & (DI - 1);
    const int rest = g >> 10;
    const int chunk = rest & (NCH - 1);
    const int b = rest >> 5;

    float a[DS], h[DS];
    const size_t base = ((size_t)((b * NCH + chunk) * DS)) * DI + d;
#pragma unroll
    for (int s = 0; s < DS; ++s) {
        a[s] = -__expf(A_log[d * DS + s]);
        h[s] = H[base + (size_t)s * DI];
    }
    const float dsk = Dskip[d];

    __shared__ float sBC[CH][2 * DS];
    for (int i = threadIdx.x; i < CH * 2 * DS; i += 256) {
        const int it = i >> 5, j = i & 31;
        const int t = t0 + (chunk * CH + it) * tstep;
        sBC[it][j] = xdb[((size_t)(b * LL + t)) * 64 + DTR + j];
    }
    __syncthreads();

    for (int it = 0; it < CH; ++it) {
        const int t = t0 + (chunk * CH + it) * tstep;
        const size_t row = (size_t)(b * LL + t);
        const float dtv = b2f(dty[row * DI + d]);
        const float u = b2f(xic[row * DI + d]);
        const float zv = b2f(xz[row * (2 * DI) + DI + d]);
        const float du = dtv * u;
        float y = 0.f;
#pragma unroll
        for (int s = 0; s < DS; ++s) {
            h[s] = fmaf(__expf(dtv * a[s]), h[s], du * sBC[it][s]);
            y = fmaf(h[s], sBC[it][DS + s], y);
        }
        y = fmaf(u, dsk, y);
        dty[row * DI + d] = __float2bfloat16(y * silu_f(zv));
    }
}

// ---------------- layernorm (fp32 in; OUT: 0=bf16 ws, 1=fp32 d_out) ----------------
template <int OUTF>
__global__ __launch_bounds__(256) void ln_kernel(
    const float* __restrict__ in, const float* __restrict__ g,
    const float* __restrict__ bta, void* __restrict__ outv)
{
    const int row = blockIdx.x;
    const int t = threadIdx.x;
    const float* p = in + (size_t)row * DM;
    const float v0 = p[t];
    const float v1 = p[t + 256];
    float sm = v0 + v1;
    float sq = v0 * v0 + v1 * v1;
#pragma unroll
    for (int off = 32; off > 0; off >>= 1) {
        sm += __shfl_xor(sm, off);
        sq += __shfl_xor(sq, off);
    }
    __shared__ float red[8];
    const int w = t >> 6;
    if ((t & 63) == 0) { red[w] = sm; red[4 + w] = sq; }
    __syncthreads();
    sm = red[0] + red[1] + red[2] + red[3];
    sq = red[4] + red[5] + red[6] + red[7];
    const float mean = sm * (1.f / DM);
    const float var = sq * (1.f / DM) - mean * mean;
    const float rstd = rsqrtf(var + 1e-5f);
    const float o0 = (v0 - mean) * rstd * g[t] + bta[t];
    const float o1 = (v1 - mean) * rstd * g[t + 256] + bta[t + 256];
    if constexpr (OUTF == 0) {
        bf16* out = (bf16*)outv;
        out[(size_t)row * DM + t] = __float2bfloat16(o0);
        out[(size_t)row * DM + t + 256] = __float2bfloat16(o1);
    } else {
        float* out = (float*)outv;
        out[(size_t)row * DM + t] = o0;
        out[(size_t)row * DM + t + 256] = o1;
    }
}

// ---------------------------------------------------------------------------
extern "C" void kernel_launch(void* const* d_in, const int* in_sizes, int n_in,
                              void* d_out, int out_size, void* d_ws, size_t ws_size,
                              hipStream_t stream)
{
    const float* x = (const float*)d_in[0];
    const float* ffn_w1 = (const float*)d_in[19];
    const float* ffn_b1 = (const float*)d_in[20];
    const float* ffn_w2 = (const float*)d_in[21];
    const float* ffn_b2 = (const float*)d_in[22];
    const float* ln1_g = (const float*)d_in[23];
    const float* ln1_b = (const float*)d_in[24];
    const float* ln2_g = (const float*)d_in[25];
    const float* ln2_b = (const float*)d_in[26];

    char* p = (char*)d_ws;
    auto alloc = [&](size_t bytes) { void* r = (void*)p; p += (bytes + 255) & ~(size_t)255; return r; };
    bf16* xz   = (bf16*)alloc((size_t)BL * 2048 * 2);
    bf16* xic  = (bf16*)alloc((size_t)BL * DI * 2);
    bf16* dtb  = (bf16*)alloc((size_t)BL * DI * 2);
    float* xdb = (float*)alloc((size_t)BL * 64 * 4);
    float* sum = (float*)alloc((size_t)BL * DM * 4);
    bf16* x1   = (bf16*)alloc((size_t)BL * DM * 2);
    bf16* xb   = (bf16*)alloc((size_t)BL * DM * 2);
    float* SD  = (float*)alloc((size_t)BB * NCH * DI * 4);
    float* Hc  = (float*)alloc((size_t)BB * NCH * DS * DI * 4);
    bf16* wip[2], *wxp[2], *wop[2];
    for (int d = 0; d < 2; ++d) {
        wip[d] = (bf16*)alloc((size_t)2 * DI * DM * 2);
        wxp[d] = (bf16*)alloc((size_t)64 * DI * 2);
        wop[d] = (bf16*)alloc((size_t)DM * DI * 2);
    }
    bf16* w1b = (bf16*)alloc((size_t)DFF * DM * 2);
    bf16* w2b = (bf16*)alloc((size_t)DM * DFF * 2);

    auto cvt = [&](const float* src, bf16* dst, size_t n) {
        int n4 = (int)(n / 4);
        cvt_kernel<<<(n4 + 255) / 256, 256, 0, stream>>>(src, dst, n4);
    };
    cvt(x, xb, (size_t)BL * DM);
    for (int d = 0; d < 2; ++d) {
        const int o = 1 + d * 9;
        cvt((const float*)d_in[o + 0], wip[d], (size_t)2 * DI * DM);
        cvt((const float*)d_in[o + 3], wxp[d], (size_t)64 * DI);
        cvt((const float*)d_in[o + 8], wop[d], (size_t)DM * DI);
    }
    cvt(ffn_w1, w1b, (size_t)DFF * DM);
    cvt(ffn_w2, w2b, (size_t)DM * DFF);

    const dim3 blk(256);
    for (int dir = 0; dir < 2; ++dir) {
        const int o = 1 + dir * 9;
        const float* conv_w = (const float*)d_in[o + 1];
        const float* conv_b = (const float*)d_in[o + 2];
        const float* dt_w   = (const float*)d_in[o + 4];
        const float* dt_b   = (const float*)d_in[o + 5];
        const float* A_log  = (const float*)d_in[o + 6];
        const float* Dskip  = (const float*)d_in[o + 7];

        const int nbr = (dir == 0) ? -1 : +1;
        const int t0 = (dir == 0) ? 0 : (LL - 1);
        const int tstep = (dir == 0) ? 1 : -1;

        // grids: x = m-tiles (BL/128 = 128), y = n-tiles
        gemm_mfma<EP_BF16, 128><<<dim3(BL / 128, (2 * DI) / 128), blk, 0, stream>>>(
            xb, DM, wip[dir], DM, xz, 2 * DI, DM, nullptr, nullptr);
        conv_silu_kernel<<<BL, blk, 0, stream>>>(xz, conv_w, conv_b, xic, nbr);
        gemm_mfma<EP_F32, 64><<<dim3(BL / 128, 1), blk, 0, stream>>>(
            xic, DI, wxp[dir], DI, xdb, 64, DI, nullptr, nullptr);
        gemm_nt<EP_SOFTPLUS, float><<<dim3(DI / 64, BL / 64), blk, 0, stream>>>(
            xdb, 64, dt_w, DTR, dtb, DI, DTR, dt_b, nullptr);

        scan_p1<<<(BB * NCH * DI) / 256, blk, 0, stream>>>(
            xic, dtb, xdb, A_log, SD, Hc, t0, tstep);
        scan_p2<<<(BB * DS * DI) / 256, blk, 0, stream>>>(SD, Hc, A_log);
        scan_p3<<<(BB * NCH * DI) / 256, blk, 0, stream>>>(
            xic, xz, xdb, dtb, A_log, Dskip, Hc, t0, tstep);

        if (dir == 0)
            gemm_mfma<EP_RESF, 128><<<dim3(BL / 128, DM / 128), blk, 0, stream>>>(
                dtb, DI, wop[dir], DI, sum, DM, DI, nullptr, x);
        else
            gemm_mfma<EP_ACC, 128><<<dim3(BL / 128, DM / 128), blk, 0, stream>>>(
                dtb, DI, wop[dir], DI, sum, DM, DI, nullptr, nullptr);
    }

    ln_kernel<0><<<BL, blk, 0, stream>>>(sum, ln1_g, ln1_b, x1);
    gemm_mfma<EP_GELU, 128><<<dim3(BL / 128, DFF / 128), blk, 0, stream>>>(
        x1, DM, w1b, DM, xz, DFF, DM, ffn_b1, nullptr);
    gemm_mfma<EP_BIASRES, 128><<<dim3(BL / 128, DM / 128), blk, 0, stream>>>(
        xz, DFF, w2b, DFF, sum, DM, DFF, ffn_b2, x1);
    ln_kernel<1><<<BL, blk, 0, stream>>>(sum, ln2_g, ln2_b, d_out);
}

// Round 12
// 863.161 us; speedup vs baseline: 1.7792x; 1.1212x over previous
//
#include <hip/hip_runtime.h>
#include <hip/hip_bf16.h>

#define BB 8
#define LL 2048
#define DM 512
#define DI 1024
#define DS 16
#define DTR 32
#define DFF 2048
#define BL (BB * LL)
#define CH 64
#define NCH (LL / CH)   // 32

typedef __hip_bfloat16 bf16;
struct bf4 { bf16 x, y, z, w; };
typedef __attribute__((ext_vector_type(8))) short short8;
typedef __attribute__((ext_vector_type(4))) float floatx4;

__device__ __forceinline__ float silu_f(float x) { return x / (1.f + __expf(-x)); }
__device__ __forceinline__ float softplus_f(float x) { return x > 20.f ? x : log1pf(__expf(x)); }
__device__ __forceinline__ float gelu_f(float x) { return 0.5f * x * (1.f + erff(x * 0.70710678118654752f)); }
__device__ __forceinline__ float b2f(bf16 v) { return __bfloat162float(v); }

__device__ __forceinline__ float4 ld4(const float* p) { return *(const float4*)p; }
__device__ __forceinline__ float4 ld4(const bf16* p) {
    bf4 v = *(const bf4*)p;
    return make_float4(b2f(v.x), b2f(v.y), b2f(v.z), b2f(v.w));
}
__device__ __forceinline__ bf4 pack4(float a, float b, float c, float d) {
    bf4 o; o.x = __float2bfloat16(a); o.y = __float2bfloat16(b);
    o.z = __float2bfloat16(c); o.w = __float2bfloat16(d); return o;
}

// async global->LDS, 16 B per lane; LDS dest = wave-uniform base + lane*16
__device__ __forceinline__ void gll16(const bf16* g, bf16* l) {
    __builtin_amdgcn_global_load_lds(
        (const __attribute__((address_space(1))) void*)g,
        (__attribute__((address_space(3))) void*)l, 16, 0, 0);
}

enum { EP_BF16, EP_SOFTPLUS, EP_GELU, EP_F32, EP_RESF, EP_ACC, EP_BIASRES };

// ---------------- fp32 -> bf16 conversion ----------------
__global__ __launch_bounds__(256) void cvt_kernel(const float* __restrict__ in,
                                                  bf16* __restrict__ out, int n4)
{
    int i = blockIdx.x * 256 + threadIdx.x;
    if (i < n4) {
        float4 v = *(const float4*)(in + (size_t)i * 4);
        *(bf4*)(out + (size_t)i * 4) = pack4(v.x, v.y, v.z, v.w);
    }
}

// ---------------- MFMA bf16 NT GEMM: C[m,n] = sum_k A[m,k]*W[n,k] ----------------
// 128xBN tile, BK=64 (2 MFMA k-steps/row), 256 threads, 16x16x32 MFMA.
// Staging via global_load_lds width-16. LDS rows are 128 B; the 16-B group index
// is XOR-swizzled with the row's low 3 bits (baked into the FETCH address) so
// fragment ds_read_b128 is 2-way only (free).
template <int EPI, int BN>
__global__ __launch_bounds__(256) void gemm_mfma(
    const bf16* __restrict__ A, int lda,
    const bf16* __restrict__ W, int ldb,
    void* __restrict__ Cv, int ldc, int K,
    const float* __restrict__ bias, const void* __restrict__ resv)
{
    constexpr int BM = 128, BK = 64;
    constexpr int NT = BN / 32;            // n-frags per wave
    constexpr int ACH_W = 4;               // A 1KB-chunks per wave (16 total)
    constexpr int WCH_W = (BN / 8) / 4;    // W chunks per wave (4 or 2)
    constexpr int PITCH = BN + 8;          // fp32 epilogue staging pitch
    constexpr int TILE_B = (BM + BN) * BK * 2;
    constexpr int STG_B = 32 * PITCH * 4;
    constexpr int SMEM_B = TILE_B > STG_B ? TILE_B : STG_B;
    __shared__ __align__(1024) char smem[SMEM_B];
    bf16* sA = (bf16*)smem;
    bf16* sW = (bf16*)(smem + BM * BK * 2);

    const int tid = threadIdx.x;
    const int wv = tid >> 6, ln = tid & 63;
    const int rch = ln >> 3;                           // row within 8-row chunk
    const int kgrp = (ln & 7) ^ (rch & 7);             // swizzled 16B-group fetch
    const int c = ln & 15, q4 = ln >> 4;               // fragment col / k-quad
    const int m0 = blockIdx.x * BM, n0 = blockIdx.y * BN;
    const int wm = (wv >> 1) * 64, wn = (wv & 1) * (BN / 2);

    floatx4 acc[4][NT] = {};

    for (int k0 = 0; k0 < K; k0 += BK) {
        __syncthreads();                   // readers of previous tile done
#pragma unroll
        for (int q = 0; q < ACH_W; ++q) {
            const int chunk = wv * ACH_W + q;
            gll16(A + (size_t)(m0 + chunk * 8 + rch) * lda + k0 + kgrp * 8,
                  sA + chunk * 512);
        }
#pragma unroll
        for (int q = 0; q < WCH_W; ++q) {
            const int chunk = wv * WCH_W + q;
            gll16(W + (size_t)(n0 + chunk * 8 + rch) * ldb + k0 + kgrp * 8,
                  sW + chunk * 512);
        }
        __syncthreads();                   // drains vmcnt(0) then barrier

#pragma unroll
        for (int kk = 0; kk < 2; ++kk) {
            short8 af[4], wf[NT];
#pragma unroll
            for (int i = 0; i < 4; ++i)
                af[i] = *(const short8*)(sA + (wm + i * 16 + c) * 64 +
                                         (((kk << 2) | q4) ^ (c & 7)) * 8);
#pragma unroll
            for (int j = 0; j < NT; ++j)
                wf[j] = *(const short8*)(sW + (wn + j * 16 + c) * 64 +
                                         (((kk << 2) | q4) ^ (c & 7)) * 8);
#pragma unroll
            for (int i = 0; i < 4; ++i)
#pragma unroll
                for (int j = 0; j < NT; ++j)
                    acc[i][j] = __builtin_amdgcn_mfma_f32_16x16x32_bf16(
                        af[i], wf[j], acc[i][j], 0, 0, 0);
        }
    }

    // ---- LDS-staged epilogue: 4 slices of 32 rows x BN cols ----
    constexpr int ELEMS = (32 * BN) / 256;
    constexpr int TPR = BN / ELEMS;
    float* sC = (float*)smem;
    const int row_l = tid / TPR;
    const int cg = (tid % TPR) * ELEMS;
    const int mg = m0 + (row_l & 15) + ((row_l >> 4) * 64);

#pragma unroll
    for (int i = 0; i < 4; ++i) {
        __syncthreads();
#pragma unroll
        for (int j = 0; j < NT; ++j)
#pragma unroll
            for (int r = 0; r < 4; ++r)
                sC[((wv >> 1) * 16 + q4 * 4 + r) * PITCH + wn + j * 16 + c] = acc[i][j][r];
        __syncthreads();

        const int m = mg + i * 16;
        const int nb = n0 + cg;
        const size_t co = (size_t)m * ldc + nb;
        float v[ELEMS];
#pragma unroll
        for (int e = 0; e < ELEMS; ++e) v[e] = sC[row_l * PITCH + cg + e];

        if constexpr (EPI == EP_BF16 || EPI == EP_GELU) {
            bf16 ov[ELEMS];
#pragma unroll
            for (int e = 0; e < ELEMS; ++e) {
                float t = v[e];
                if constexpr (EPI == EP_GELU) t = gelu_f(t + bias[nb + e]);
                ov[e] = __float2bfloat16(t);
            }
#pragma unroll
            for (int q = 0; q < ELEMS / 8; ++q)
                *(uint4*)((bf16*)Cv + co + q * 8) = *(const uint4*)(ov + q * 8);
        } else {
#pragma unroll
            for (int e = 0; e < ELEMS; ++e) {
                if constexpr (EPI == EP_RESF)
                    v[e] += ((const float*)resv)[co + e];
                else if constexpr (EPI == EP_ACC)
                    v[e] += ((const float*)Cv)[co + e];
                else if constexpr (EPI == EP_BIASRES)
                    v[e] += bias[nb + e] + b2f(((const bf16*)resv)[co + e]);
            }
#pragma unroll
            for (int q = 0; q < ELEMS / 4; ++q) {
                float4 o = {v[q * 4 + 0], v[q * 4 + 1], v[q * 4 + 2], v[q * 4 + 3]};
                *(float4*)((float*)Cv + co + q * 4) = o;
            }
        }
    }
}

// ---------------- VALU NT GEMM (kept for dt: K=32) ----------------
template <int EPI, typename TA>
__global__ __launch_bounds__(256) void gemm_nt(
    const TA* __restrict__ A, int lda,
    const float* __restrict__ W, int ldb,
    void* __restrict__ Cv, int ldc,
    int K,
    const float* __restrict__ bias,
    const void* __restrict__ resv)
{
    __shared__ float As[16][64];
    __shared__ float Bs[16][64];
    const int tid = threadIdx.x;
    const int tx = tid & 15, ty = tid >> 4;
    const int m0 = blockIdx.y * 64, n0 = blockIdx.x * 64;
    const int lrow = tid >> 2;
    const int lcol = (tid & 3) << 2;

    const TA* Ap = A + (size_t)(m0 + lrow) * lda + lcol;
    const float* Bp = W + (size_t)(n0 + lrow) * ldb + lcol;

    float acc[4][4] = {};

    for (int k0 = 0; k0 < K; k0 += 16) {
        float4 av = ld4(Ap + k0);
        float4 bv = ld4(Bp + k0);
        __syncthreads();
        As[lcol + 0][lrow] = av.x; As[lcol + 1][lrow] = av.y;
        As[lcol + 2][lrow] = av.z; As[lcol + 3][lrow] = av.w;
        Bs[lcol + 0][lrow] = bv.x; Bs[lcol + 1][lrow] = bv.y;
        Bs[lcol + 2][lrow] = bv.z; Bs[lcol + 3][lrow] = bv.w;
        __syncthreads();
#pragma unroll
        for (int kk = 0; kk < 16; ++kk) {
            float4 a4 = *(const float4*)(&As[kk][ty << 2]);
            float4 b4 = *(const float4*)(&Bs[kk][tx << 2]);
            float aa[4] = {a4.x, a4.y, a4.z, a4.w};
            float bb[4] = {b4.x, b4.y, b4.z, b4.w};
#pragma unroll
            for (int i = 0; i < 4; ++i)
#pragma unroll
                for (int j = 0; j < 4; ++j)
                    acc[i][j] = fmaf(aa[i], bb[j], acc[i][j]);
        }
    }

#pragma unroll
    for (int i = 0; i < 4; ++i) {
        const int m = m0 + (ty << 2) + i;
        const int n = n0 + (tx << 2);
        float v[4] = {acc[i][0], acc[i][1], acc[i][2], acc[i][3]};
        const size_t co = (size_t)m * ldc + n;
        if constexpr (EPI == EP_SOFTPLUS) {
            *(bf4*)((bf16*)Cv + co) = pack4(
                softplus_f(v[0] + bias[n + 0]), softplus_f(v[1] + bias[n + 1]),
                softplus_f(v[2] + bias[n + 2]), softplus_f(v[3] + bias[n + 3]));
        } else if constexpr (EPI == EP_F32) {
            float4 o = {v[0], v[1], v[2], v[3]};
            *(float4*)((float*)Cv + co) = o;
        }
    }
}

// ---------------- depthwise conv (D_CONV=2) + SiLU ----------------
__global__ __launch_bounds__(256) void conv_silu_kernel(
    const bf16* __restrict__ xz, const float* __restrict__ cw,
    const float* __restrict__ cb, bf16* __restrict__ xic, int nbr)
{
    const int idx = blockIdx.x * 256 + threadIdx.x;
    const int c4 = (idx & 255) << 2;
    const int row = idx >> 8;
    const int l = row & (LL - 1);
    const int lnbr = l + nbr;
    const bool valid = (lnbr >= 0) && (lnbr < LL);

    const bf16* pc = xz + (size_t)row * (2 * DI) + c4;
    float4 cur = ld4(pc);
    float4 prv = make_float4(0.f, 0.f, 0.f, 0.f);
    if (valid) prv = ld4(pc + (ptrdiff_t)nbr * (2 * DI));

    float w0[4], w1[4];
#pragma unroll
    for (int q = 0; q < 4; ++q) { w0[q] = cw[(c4 + q) * 2]; w1[q] = cw[(c4 + q) * 2 + 1]; }
    float4 bb = ld4(cb + c4);

    *(bf4*)(xic + (size_t)row * DI + c4) = pack4(
        silu_f(fmaf(w0[0], prv.x, fmaf(w1[0], cur.x, bb.x))),
        silu_f(fmaf(w0[1], prv.y, fmaf(w1[1], cur.y, bb.y))),
        silu_f(fmaf(w0[2], prv.z, fmaf(w1[2], cur.z, bb.z))),
        silu_f(fmaf(w0[3], prv.w, fmaf(w1[3], cur.w, bb.w))));
}

// ---------------- chunked selective scan (CH=64, NCH=32) ----------------
// A_log in this problem is log(broadcast(1..16)) => a[s] = -(s+1); fast path
// computes exp(-dt) once and takes powers (1 transcendental instead of 16).
// Generic fallback keeps correctness for arbitrary A_log.
__global__ __launch_bounds__(256) void scan_p1(
    const bf16* __restrict__ xic, const bf16* __restrict__ dtb,
    const float* __restrict__ xdb, const float* __restrict__ A_log,
    float* __restrict__ SD, float* __restrict__ H, int t0, int tstep)
{
    const int g = blockIdx.x * 256 + threadIdx.x;
    const int d = g & (DI - 1);
    const int rest = g >> 10;
    const int chunk = rest & (NCH - 1);
    const int b = rest >> 5;

    float a[DS], h[DS];
    bool fast = true;
#pragma unroll
    for (int s = 0; s < DS; ++s) {
        a[s] = -__expf(A_log[d * DS + s]);
        h[s] = 0.f;
        fast = fast && (fabsf(a[s] + (float)(s + 1)) < 1e-3f * (s + 1));
    }

    __shared__ float sB[CH][DS];
    for (int i = threadIdx.x; i < CH * DS; i += 256) {
        const int it = i >> 4, s = i & 15;
        const int t = t0 + (chunk * CH + it) * tstep;
        sB[it][s] = xdb[((size_t)(b * LL + t)) * 64 + DTR + s];
    }
    __syncthreads();

    float sumdt = 0.f;
    if (fast) {
        for (int it = 0; it < CH; ++it) {
            const int t = t0 + (chunk * CH + it) * tstep;
            const size_t row = (size_t)(b * LL + t);
            const float dtv = b2f(dtb[row * DI + d]);
            const float u = b2f(xic[row * DI + d]);
            sumdt += dtv;
            const float du = dtv * u;
            const float e = __expf(-dtv);
            float dA = 1.f;
#pragma unroll
            for (int s = 0; s < DS; ++s) {
                dA *= e;
                h[s] = fmaf(dA, h[s], du * sB[it][s]);
            }
        }
    } else {
        for (int it = 0; it < CH; ++it) {
            const int t = t0 + (chunk * CH + it) * tstep;
            const size_t row = (size_t)(b * LL + t);
            const float dtv = b2f(dtb[row * DI + d]);
            const float u = b2f(xic[row * DI + d]);
            sumdt += dtv;
            const float du = dtv * u;
#pragma unroll
            for (int s = 0; s < DS; ++s)
                h[s] = fmaf(__expf(dtv * a[s]), h[s], du * sB[it][s]);
        }
    }
    SD[((size_t)(b * NCH + chunk)) * DI + d] = sumdt;
    const size_t base = ((size_t)((b * NCH + chunk) * DS)) * DI + d;
#pragma unroll
    for (int s = 0; s < DS; ++s)
        H[base + (size_t)s * DI] = h[s];
}

__global__ __launch_bounds__(256) void scan_p2(
    const float* __restrict__ SD, float* __restrict__ H,
    const float* __restrict__ A_log)
{
    const int g = blockIdx.x * 256 + threadIdx.x;   // 131072 threads
    const int d = g & (DI - 1);
    const int rest = g >> 10;
    const int s = rest & 15;
    const int b = rest >> 4;
    const float a = -__expf(A_log[d * DS + s]);
    float h = 0.f;
    for (int c = 0; c < NCH; ++c) {
        const float sd = SD[((size_t)(b * NCH + c)) * DI + d];
        const size_t idx = ((size_t)((b * NCH + c) * DS + s)) * DI + d;
        const float Pv = __expf(a * sd);
        const float Hv = H[idx];
        H[idx] = h;
        h = fmaf(Pv, h, Hv);
    }
}

__global__ __launch_bounds__(256) void scan_p3(
    const bf16* __restrict__ xic, const bf16* __restrict__ xz,
    const float* __restrict__ xdb, bf16* __restrict__ dty,
    const float* __restrict__ A_log, const float* __restrict__ Dskip,
    const float* __restrict__ H, int t0, int tstep)
{
    const int g = blockIdx.x * 256 + threadIdx.x;
    const int d = g & (DI - 1);
    const int rest = g >> 10;
    const int chunk = rest & (NCH - 1);
    const int b = rest >> 5;

    float a[DS], h[DS];
    bool fast = true;
    const size_t base = ((size_t)((b * NCH + chunk) * DS)) * DI + d;
#pragma unroll
    for (int s = 0; s < DS; ++s) {
        a[s] = -__expf(A_log[d * DS + s]);
        h[s] = H[base + (size_t)s * DI];
        fast = fast && (fabsf(a[s] + (float)(s + 1)) < 1e-3f * (s + 1));
    }
    const float dsk = Dskip[d];

    __shared__ float sBC[CH][2 * DS];
    for (int i = threadIdx.x; i < CH * 2 * DS; i += 256) {
        const int it = i >> 5, j = i & 31;
        const int t = t0 + (chunk * CH + it) * tstep;
        sBC[it][j] = xdb[((size_t)(b * LL + t)) * 64 + DTR + j];
    }
    __syncthreads();

    if (fast) {
        for (int it = 0; it < CH; ++it) {
            const int t = t0 + (chunk * CH + it) * tstep;
            const size_t row = (size_t)(b * LL + t);
            const float dtv = b2f(dty[row * DI + d]);
            const float u = b2f(xic[row * DI + d]);
            const float zv = b2f(xz[row * (2 * DI) + DI + d]);
            const float du = dtv * u;
            const float e = __expf(-dtv);
            float dA = 1.f, y = 0.f;
#pragma unroll
            for (int s = 0; s < DS; ++s) {
                dA *= e;
                h[s] = fmaf(dA, h[s], du * sBC[it][s]);
                y = fmaf(h[s], sBC[it][DS + s], y);
            }
            y = fmaf(u, dsk, y);
            dty[row * DI + d] = __float2bfloat16(y * silu_f(zv));
        }
    } else {
        for (int it = 0; it < CH; ++it) {
            const int t = t0 + (chunk * CH + it) * tstep;
            const size_t row = (size_t)(b * LL + t);
            const float dtv = b2f(dty[row * DI + d]);
            const float u = b2f(xic[row * DI + d]);
            const float zv = b2f(xz[row * (2 * DI) + DI + d]);
            const float du = dtv * u;
            float y = 0.f;
#pragma unroll
            for (int s = 0; s < DS; ++s) {
                h[s] = fmaf(__expf(dtv * a[s]), h[s], du * sBC[it][s]);
                y = fmaf(h[s], sBC[it][DS + s], y);
            }
            y = fmaf(u, dsk, y);
            dty[row * DI + d] = __float2bfloat16(y * silu_f(zv));
        }
    }
}

// ---------------- layernorm (fp32 in; OUT: 0=bf16 ws, 1=fp32 d_out) ----------------
template <int OUTF>
__global__ __launch_bounds__(256) void ln_kernel(
    const float* __restrict__ in, const float* __restrict__ g,
    const float* __restrict__ bta, void* __restrict__ outv)
{
    const int row = blockIdx.x;
    const int t = threadIdx.x;
    const float* p = in + (size_t)row * DM;
    const float v0 = p[t];
    const float v1 = p[t + 256];
    float sm = v0 + v1;
    float sq = v0 * v0 + v1 * v1;
#pragma unroll
    for (int off = 32; off > 0; off >>= 1) {
        sm += __shfl_xor(sm, off);
        sq += __shfl_xor(sq, off);
    }
    __shared__ float red[8];
    const int w = t >> 6;
    if ((t & 63) == 0) { red[w] = sm; red[4 + w] = sq; }
    __syncthreads();
    sm = red[0] + red[1] + red[2] + red[3];
    sq = red[4] + red[5] + red[6] + red[7];
    const float mean = sm * (1.f / DM);
    const float var = sq * (1.f / DM) - mean * mean;
    const float rstd = rsqrtf(var + 1e-5f);
    const float o0 = (v0 - mean) * rstd * g[t] + bta[t];
    const float o1 = (v1 - mean) * rstd * g[t + 256] + bta[t + 256];
    if constexpr (OUTF == 0) {
        bf16* out = (bf16*)outv;
        out[(size_t)row * DM + t] = __float2bfloat16(o0);
        out[(size_t)row * DM + t + 256] = __float2bfloat16(o1);
    } else {
        float* out = (float*)outv;
        out[(size_t)row * DM + t] = o0;
        out[(size_t)row * DM + t + 256] = o1;
    }
}

// ---------------------------------------------------------------------------
extern "C" void kernel_launch(void* const* d_in, const int* in_sizes, int n_in,
                              void* d_out, int out_size, void* d_ws, size_t ws_size,
                              hipStream_t stream)
{
    const float* x = (const float*)d_in[0];
    const float* ffn_w1 = (const float*)d_in[19];
    const float* ffn_b1 = (const float*)d_in[20];
    const float* ffn_w2 = (const float*)d_in[21];
    const float* ffn_b2 = (const float*)d_in[22];
    const float* ln1_g = (const float*)d_in[23];
    const float* ln1_b = (const float*)d_in[24];
    const float* ln2_g = (const float*)d_in[25];
    const float* ln2_b = (const float*)d_in[26];

    char* p = (char*)d_ws;
    auto alloc = [&](size_t bytes) { void* r = (void*)p; p += (bytes + 255) & ~(size_t)255; return r; };
    bf16* xz   = (bf16*)alloc((size_t)BL * 2048 * 2);
    bf16* xic  = (bf16*)alloc((size_t)BL * DI * 2);
    bf16* dtb  = (bf16*)alloc((size_t)BL * DI * 2);
    float* xdb = (float*)alloc((size_t)BL * 64 * 4);
    float* sum = (float*)alloc((size_t)BL * DM * 4);
    bf16* x1   = (bf16*)alloc((size_t)BL * DM * 2);
    bf16* xb   = (bf16*)alloc((size_t)BL * DM * 2);
    float* SD  = (float*)alloc((size_t)BB * NCH * DI * 4);
    float* Hc  = (float*)alloc((size_t)BB * NCH * DS * DI * 4);
    bf16* wip[2], *wxp[2], *wop[2];
    for (int d = 0; d < 2; ++d) {
        wip[d] = (bf16*)alloc((size_t)2 * DI * DM * 2);
        wxp[d] = (bf16*)alloc((size_t)64 * DI * 2);
        wop[d] = (bf16*)alloc((size_t)DM * DI * 2);
    }
    bf16* w1b = (bf16*)alloc((size_t)DFF * DM * 2);
    bf16* w2b = (bf16*)alloc((size_t)DM * DFF * 2);

    auto cvt = [&](const float* src, bf16* dst, size_t n) {
        int n4 = (int)(n / 4);
        cvt_kernel<<<(n4 + 255) / 256, 256, 0, stream>>>(src, dst, n4);
    };
    cvt(x, xb, (size_t)BL * DM);
    for (int d = 0; d < 2; ++d) {
        const int o = 1 + d * 9;
        cvt((const float*)d_in[o + 0], wip[d], (size_t)2 * DI * DM);
        cvt((const float*)d_in[o + 3], wxp[d], (size_t)64 * DI);
        cvt((const float*)d_in[o + 8], wop[d], (size_t)DM * DI);
    }
    cvt(ffn_w1, w1b, (size_t)DFF * DM);
    cvt(ffn_w2, w2b, (size_t)DM * DFF);

    const dim3 blk(256);
    for (int dir = 0; dir < 2; ++dir) {
        const int o = 1 + dir * 9;
        const float* conv_w = (const float*)d_in[o + 1];
        const float* conv_b = (const float*)d_in[o + 2];
        const float* dt_w   = (const float*)d_in[o + 4];
        const float* dt_b   = (const float*)d_in[o + 5];
        const float* A_log  = (const float*)d_in[o + 6];
        const float* Dskip  = (const float*)d_in[o + 7];

        const int nbr = (dir == 0) ? -1 : +1;
        const int t0 = (dir == 0) ? 0 : (LL - 1);
        const int tstep = (dir == 0) ? 1 : -1;

        // grids: x = m-tiles (BL/128 = 128), y = n-tiles
        gemm_mfma<EP_BF16, 128><<<dim3(BL / 128, (2 * DI) / 128), blk, 0, stream>>>(
            xb, DM, wip[dir], DM, xz, 2 * DI, DM, nullptr, nullptr);
        conv_silu_kernel<<<BL, blk, 0, stream>>>(xz, conv_w, conv_b, xic, nbr);
        gemm_mfma<EP_F32, 64><<<dim3(BL / 128, 1), blk, 0, stream>>>(
            xic, DI, wxp[dir], DI, xdb, 64, DI, nullptr, nullptr);
        gemm_nt<EP_SOFTPLUS, float><<<dim3(DI / 64, BL / 64), blk, 0, stream>>>(
            xdb, 64, dt_w, DTR, dtb, DI, DTR, dt_b, nullptr);

        scan_p1<<<(BB * NCH * DI) / 256, blk, 0, stream>>>(
            xic, dtb, xdb, A_log, SD, Hc, t0, tstep);
        scan_p2<<<(BB * DS * DI) / 256, blk, 0, stream>>>(SD, Hc, A_log);
        scan_p3<<<(BB * NCH * DI) / 256, blk, 0, stream>>>(
            xic, xz, xdb, dtb, A_log, Dskip, Hc, t0, tstep);

        if (dir == 0)
            gemm_mfma<EP_RESF, 128><<<dim3(BL / 128, DM / 128), blk, 0, stream>>>(
                dtb, DI, wop[dir], DI, sum, DM, DI, nullptr, x);
        else
            gemm_mfma<EP_ACC, 128><<<dim3(BL / 128, DM / 128), blk, 0, stream>>>(
                dtb, DI, wop[dir], DI, sum, DM, DI, nullptr, nullptr);
    }

    ln_kernel<0><<<BL, blk, 0, stream>>>(sum, ln1_g, ln1_b, x1);
    gemm_mfma<EP_GELU, 128><<<dim3(BL / 128, DFF / 128), blk, 0, stream>>>(
        x1, DM, w1b, DM, xz, DFF, DM, ffn_b1, nullptr);
    gemm_mfma<EP_BIASRES, 128><<<dim3(BL / 128, DM / 128), blk, 0, stream>>>(
        xz, DFF, w2b, DFF, sum, DM, DFF, ffn_b2, x1);
    ln_kernel<1><<<BL, blk, 0, stream>>>(sum, ln2_g, ln2_b, d_out);
}